// Round 6
// baseline (953.825 us; speedup 1.0000x reference)
//
#include <hip/hip_runtime.h>
#include <cstdint>
#include <cstddef>

#define N_NODES 30000
#define N_EDGES 480000
#define EP_EDGES (N_EDGES + N_NODES)   // 510000, with self-loops appended
#define DIM 100
#define NH 4
#define NL 6
#define NG 128
#define KP 416                         // GEMM2 K padded to 13*32

// ---------------------------------------------------------------------------
// Workspace layout (bytes). Peak ~88.6 MB (known-good bound: 112.5 MB).
#define OFF_H       0u            // float [30000][100]
#define OFF_AGG2    12000000u     // fp16  [30000][416]  (24.96 MB, loop only)
#define OFF_EID     12000000u     // int   [510000]   (overlay, pre-loop: csr slot -> edge id, -1=self-loop)
#define OFF_DEG     14040000u     // int   [30000]    (overlay, pre-loop)
#define OFF_CURS    14160000u     // int   [30000]    (overlay, pre-loop)
#define OFF_ETMP    16000000u     // fp16  [480000][24] edge-order scores (overlay, pre-loop, 23.04 MB)
#define OFF_POOL    12000000u     // float [128][100] (overlay, post-loop)
#define OFF_CNT     12051200u     // float [128]      (overlay, post-loop)
#define OFF_SCI     60000000u     // float [30000][4]
#define OFF_SCJ     60480000u     // float [30000][4]
#define OFF_ESC     60960000u     // fp16  [6][510000][4]  (CSR order!)
#define OFF_CWIJ    85440000u     // float [6][100][8]  (c = isJ*4 + h)
#define OFF_WR      85469184u     // fp16  Bfrag [6][7][13][64][8]  (559 KB)
#define OFF_INDPTR  86429184u     // int   [30001]
#define OFF_CSRS    86549248u     // int   [510000]
#define OFF_BSUM    88589248u     // int   [32]
#define OFF_BW      88589376u     // fp16  Bw [2(hl)][2(ct)][4(ks)][64][8]  (16 KB, escore MFMA B)

typedef _Float16 half8 __attribute__((ext_vector_type(8)));
typedef __fp16 fp16x2 __attribute__((ext_vector_type(2)));
typedef float f32x4 __attribute__((ext_vector_type(4)));

static __device__ __forceinline__ unsigned short f2h(float f) {
  return __builtin_bit_cast(unsigned short, (_Float16)f);
}
static __device__ __forceinline__ float h2f(unsigned short u) {
  return (float)__builtin_bit_cast(_Float16, u);
}

// ---------------------------------------------------------------------------
__global__ __launch_bounds__(256) void k_init(const int* __restrict__ x,
                                              const float* __restrict__ emb,
                                              float* __restrict__ h,
                                              int* __restrict__ deg, int* __restrict__ cursor) {
  int tid = blockIdx.x * 256 + threadIdx.x;
  if (tid < N_NODES * DIM) {
    int n = tid / DIM;
    int d = tid - n * DIM;
    h[tid] = emb[x[n] * DIM + d];
  }
  if (tid < N_NODES) { deg[tid] = 0; cursor[tid] = 0; }
}

// fold W,We with a_i/a_j:
//  - cWij[l][k][c] (c=isJ*4+h)  for k_score
//  - Bw: escore MFMA B-operand, split precision (hl=0: f16(v), hl=1: f16(v-f32(f16(v)))).
//    Entry (hl,ct,ks,lane,j) = folded We.a_j for col c=ct*16+(lane&15) (=l*4+h),
//    k = ks*32 + (lane>>4)*8 + j; zero outside c<24 || k<100.
__global__ __launch_bounds__(256) void k_fold(const float* __restrict__ W,
                                              const float* __restrict__ We,
                                              const float* __restrict__ a,
                                              float* __restrict__ cWij,
                                              unsigned short* __restrict__ Bw) {
  int tid = blockIdx.x * 256 + threadIdx.x;
  if (tid < NL * DIM * 8) {
    int l = tid / 800, r = tid % 800;
    int k = r >> 3, c = r & 7;
    int hh = c & 3, isJ = c >> 2;
    const float* wp = W + (size_t)(l * 400 + hh * 100) * 100 + k;
    const float* ap = a + (size_t)(l * 4 + hh) * 200 + isJ * 100;
    float s = 0.f;
    for (int d = 0; d < 100; ++d) s += wp[(size_t)d * 100] * ap[d];
    cWij[l * 800 + k * 8 + c] = s;
  } else if (tid < NL * DIM * 8 + DIM * 24) {
    int m = tid - NL * DIM * 8;
    int k = m / 24, c = m % 24;
    int l = c >> 2, hh = c & 3;
    const float* wp = We + (size_t)(l * 400 + hh * 100) * 100 + k;
    const float* ap = a + (size_t)(l * 4 + hh) * 200 + 100;
    float s = 0.f;
    for (int d = 0; d < 100; ++d) s += wp[(size_t)d * 100] * ap[d];
    // split precision + scatter into MFMA B-operand order
    _Float16 vh = (_Float16)s;
    _Float16 vl = (_Float16)(s - (float)vh);
    int ct = c >> 4;
    int lane = (((k & 31) >> 3) << 4) | (c & 15);
    int ks = k >> 5;
    int j = k & 7;
    Bw[(size_t)(((0 * 2 + ct) * 4 + ks) * 64 + lane) * 8 + j] = __builtin_bit_cast(unsigned short, vh);
    Bw[(size_t)(((1 * 2 + ct) * 4 + ks) * 64 + lane) * 8 + j] = __builtin_bit_cast(unsigned short, vl);
  } else if (tid < NL * DIM * 8 + DIM * 24 + 8192) {
    // zero-fill the invalid (padding) Bw entries; disjoint from valid writes.
    int E = tid - (NL * DIM * 8 + DIM * 24);
    int j = E & 7;
    int lane = (E >> 3) & 63;
    int rest = E >> 9;          // [0,16)
    int ks = rest & 3;
    int ct = (rest >> 2) & 1;
    int c = ct * 16 + (lane & 15);
    int k = ks * 32 + ((lane >> 4) << 3) + j;
    if (!(c < 24 && k < 100)) Bw[E] = 0;
  }
}

// Bfrag[l][ct][ks][lane][j] (f16) = B[k][n] in MFMA B-operand order:
//   k = ks*32 + (lane>>4)*8 + j,  n = ct*16 + (lane&15)
//   B[k=hh*100+kk][n] = W[l][hh*100 + n][kk]   (zeros in pads)
__global__ __launch_bounds__(256) void k_bfrag(const float* __restrict__ W,
                                               unsigned short* __restrict__ Bfrag) {
  int tid = blockIdx.x * 256 + threadIdx.x;
  if (tid >= NL * 7 * 13 * 64 * 8) return;
  int j = tid & 7;
  int lane = (tid >> 3) & 63;
  int rest = tid >> 9;          // ((l*7+ct)*13+ks)
  int ks = rest % 13;
  int rest2 = rest / 13;
  int ct = rest2 % 7;
  int l = rest2 / 7;
  int k = ks * 32 + ((lane >> 4) << 3) + j;
  int n = ct * 16 + (lane & 15);
  float v = 0.f;
  if (k < 400 && n < 100) {
    int hh = k / 100, kk = k - hh * 100;
    v = W[(size_t)(l * 400 + hh * 100 + n) * 100 + kk];
  }
  Bfrag[tid] = f2h(v);
}

__global__ __launch_bounds__(256) void k_deg(const int* __restrict__ ei, int* __restrict__ deg) {
  int tid = blockIdx.x * 256 + threadIdx.x;
  if (tid >= EP_EDGES) return;
  int dstn = (tid < N_EDGES) ? ei[N_EDGES + tid] : (tid - N_EDGES);
  atomicAdd(&deg[dstn], 1);
}

// two-level scan: per-block inclusive scan (30 blocks x 1024)
__global__ __launch_bounds__(1024) void k_scan1(const int* __restrict__ deg,
                                                int* __restrict__ indptr, int* __restrict__ bsum) {
  __shared__ int s[1024];
  int t = threadIdx.x;
  int i = blockIdx.x * 1024 + t;
  int v = (i < N_NODES) ? deg[i] : 0;
  s[t] = v;
  __syncthreads();
  for (int off = 1; off < 1024; off <<= 1) {
    int tmp = (t >= off) ? s[t - off] : 0;
    __syncthreads();
    s[t] += tmp;
    __syncthreads();
  }
  if (i < N_NODES) indptr[i + 1] = s[t];
  if (t == 1023) bsum[blockIdx.x] = s[1023];
}
// scan 30 block sums -> exclusive offsets (1 wave)
__global__ __launch_bounds__(64) void k_scan2(int* __restrict__ bsum) {
  int t = threadIdx.x;
  int v = (t < 30) ? bsum[t] : 0;
  int inc = v;
  for (int off = 1; off < 64; off <<= 1) {
    int up = __shfl_up(inc, off);
    if (t >= off) inc += up;
  }
  if (t < 30) bsum[t] = inc - v;   // exclusive
}
__global__ __launch_bounds__(1024) void k_scan3(int* __restrict__ indptr,
                                                const int* __restrict__ bsum) {
  int i = blockIdx.x * 1024 + threadIdx.x;
  if (i < N_NODES) indptr[i + 1] += bsum[blockIdx.x];
  if (i == 0) indptr[0] = 0;
}

// build CSR; record inverse permutation csr_eid[p] = edge id (-1 for self-loop)
__global__ __launch_bounds__(256) void k_scatter(const int* __restrict__ ei,
                                                 const int* __restrict__ indptr,
                                                 int* __restrict__ cursor,
                                                 int* __restrict__ csr_src,
                                                 int* __restrict__ csr_eid) {
  int tid = blockIdx.x * 256 + threadIdx.x;
  if (tid >= EP_EDGES) return;
  int dstn = (tid < N_EDGES) ? ei[N_EDGES + tid] : (tid - N_EDGES);
  int srcn = (tid < N_EDGES) ? ei[tid] : (tid - N_EDGES);
  int p = indptr[dstn] + atomicAdd(&cursor[dstn], 1);
  csr_src[p] = srcn;
  csr_eid[p] = (tid < N_EDGES) ? tid : -1;
}

// esc_tmp[e][l*4+h] = fp16( edge_attr[e,:] . cWe[l*4+h,:] ), EDGE order, via
// MFMA 16x16x32 f16 with split-precision compensation:
//   score = xh@wh + xl@wh + xh@wl   (residual ~2^-20 rel; f32-equivalent)
// B-operand (weights, 16 half8) lives in VGPRs for the whole kernel.
// A: 64 edge rows staged f32 into XOR-swizzled LDS (conflict-free b128 reads),
// hi/lo split on the fly. One-shot blocks: 7500 x 256 (4 waves, wave = 16 rows).
__global__ __launch_bounds__(256, 4) void k_escore(const float* __restrict__ ea,
                                                   const unsigned short* __restrict__ Bw,
                                                   unsigned short* __restrict__ esc_tmp) {
  __shared__ __align__(16) float s_ea[64 * 128];   // 32 KB, [row][128 f32], swizzled
  int t = threadIdx.x;
  int lane = t & 63;
  int wv = t >> 6;

  // ---- B fragments: load once, keep in VGPRs (16 half8 = 64 VGPRs) ----
  const half8* bp = (const half8*)Bw;
  half8 Bh[2][4], Bl[2][4];
#pragma unroll
  for (int ct = 0; ct < 2; ++ct)
#pragma unroll
    for (int ks = 0; ks < 4; ++ks) {
      Bh[ct][ks] = bp[((0 * 2 + ct) * 4 + ks) * 64 + lane];
      Bl[ct][ks] = bp[((1 * 2 + ct) * 4 + ks) * 64 + lane];
    }

  // ---- stage tile: zero K-pad chunks + 64 rows x 25 float4, swizzled ----
  int e0 = blockIdx.x * 64;
  const float4* g4 = (const float4*)(ea + (size_t)e0 * 100);
  for (int z = t; z < 448; z += 256) {          // rows x chunks 25..31 (k 100..127)
    int zr = z / 7, zc = z - zr * 7;
    int o = 400 + zc * 16;
    *(float4*)((char*)s_ea + zr * 512 + (o ^ ((zr & 7) << 4))) = (float4){0.f, 0.f, 0.f, 0.f};
  }
#pragma unroll
  for (int i = 0; i < 7; ++i) {
    int v = i * 256 + t;
    if (i < 6 || v < 1600) {
      float4 val = g4[v];
      int r = v / 25, kk = v - r * 25;
      *(float4*)((char*)s_ea + r * 512 + ((kk * 16) ^ ((r & 7) << 4))) = val;
    }
  }
  __syncthreads();

  // ---- MFMA main: wave wv handles edge rows wv*16 .. +15 ----
  int c = lane & 15;
  int quad = lane >> 4;
  int lrow = wv * 16 + c;                 // A-operand row for this lane
  int swz = (lrow & 7) << 4;
  const char* base = (const char*)s_ea + lrow * 512;
  f32x4 acc0 = (f32x4){0.f, 0.f, 0.f, 0.f};
  f32x4 acc1 = (f32x4){0.f, 0.f, 0.f, 0.f};
#pragma unroll
  for (int ks = 0; ks < 4; ++ks) {
    int o = ks * 128 + quad * 32;
    float4 xa = *(const float4*)(base + ((o) ^ swz));
    float4 xb = *(const float4*)(base + ((o + 16) ^ swz));
    fp16x2 h0 = __builtin_amdgcn_cvt_pkrtz(xa.x, xa.y);
    fp16x2 h1 = __builtin_amdgcn_cvt_pkrtz(xa.z, xa.w);
    fp16x2 h2 = __builtin_amdgcn_cvt_pkrtz(xb.x, xb.y);
    fp16x2 h3 = __builtin_amdgcn_cvt_pkrtz(xb.z, xb.w);
    fp16x2 l0 = __builtin_amdgcn_cvt_pkrtz(xa.x - (float)h0[0], xa.y - (float)h0[1]);
    fp16x2 l1 = __builtin_amdgcn_cvt_pkrtz(xa.z - (float)h1[0], xa.w - (float)h1[1]);
    fp16x2 l2 = __builtin_amdgcn_cvt_pkrtz(xb.x - (float)h2[0], xb.y - (float)h2[1]);
    fp16x2 l3 = __builtin_amdgcn_cvt_pkrtz(xb.z - (float)h3[0], xb.w - (float)h3[1]);
    uint4 uh = {__builtin_bit_cast(unsigned, h0), __builtin_bit_cast(unsigned, h1),
                __builtin_bit_cast(unsigned, h2), __builtin_bit_cast(unsigned, h3)};
    uint4 ul = {__builtin_bit_cast(unsigned, l0), __builtin_bit_cast(unsigned, l1),
                __builtin_bit_cast(unsigned, l2), __builtin_bit_cast(unsigned, l3)};
    half8 xh = __builtin_bit_cast(half8, uh);
    half8 xl = __builtin_bit_cast(half8, ul);
    acc0 = __builtin_amdgcn_mfma_f32_16x16x32_f16(xh, Bh[0][ks], acc0, 0, 0, 0);
    acc0 = __builtin_amdgcn_mfma_f32_16x16x32_f16(xl, Bh[0][ks], acc0, 0, 0, 0);
    acc0 = __builtin_amdgcn_mfma_f32_16x16x32_f16(xh, Bl[0][ks], acc0, 0, 0, 0);
    acc1 = __builtin_amdgcn_mfma_f32_16x16x32_f16(xh, Bh[1][ks], acc1, 0, 0, 0);
    acc1 = __builtin_amdgcn_mfma_f32_16x16x32_f16(xl, Bh[1][ks], acc1, 0, 0, 0);
    acc1 = __builtin_amdgcn_mfma_f32_16x16x32_f16(xh, Bl[1][ks], acc1, 0, 0, 0);
  }

  // ---- epilogue: C/D col=lane&15, row=quad*4+r. cols: ct0 -> c, ct1 -> 16+c ----
  unsigned short* orow = esc_tmp + (size_t)(e0 + wv * 16 + quad * 4) * 24;
#pragma unroll
  for (int r = 0; r < 4; ++r) {
    unsigned short* op = orow + r * 24;
    op[c] = f2h(acc0[r]);
    if (c < 8) op[16 + c] = f2h(acc1[r]);
  }
}

// permute edge-order scores into CSR order, all 6 layers per slot.
// Random 48B (one line) read per real edge; fully coalesced 6x8B writes.
// Self-loop slots (eid = -1) write zeros.
__global__ __launch_bounds__(256) void k_permute(const unsigned short* __restrict__ esc_tmp,
                                                 const int* __restrict__ csr_eid,
                                                 unsigned short* __restrict__ esc) {
  int p = blockIdx.x * 256 + threadIdx.x;
  if (p >= EP_EDGES) return;
  int e = csr_eid[p];
  ushort4 v[NL];
  if (e >= 0) {
    const unsigned short* rp = esc_tmp + (size_t)e * 24;
#pragma unroll
    for (int l = 0; l < NL; ++l) v[l] = *(const ushort4*)(rp + l * 4);
  } else {
#pragma unroll
    for (int l = 0; l < NL; ++l) { v[l].x = 0; v[l].y = 0; v[l].z = 0; v[l].w = 0; }
  }
#pragma unroll
  for (int l = 0; l < NL; ++l)
    *(ushort4*)(esc + ((size_t)l * EP_EDGES + p) * 4) = v[l];
}

// per-node attention scores: sc_i[n,h], sc_j[n,h]
__global__ __launch_bounds__(256) void k_score(const float* __restrict__ h,
                                               const float* __restrict__ cw,  // [100][8]
                                               float* __restrict__ sc_i, float* __restrict__ sc_j) {
  __shared__ __align__(16) float s[DIM * 8];
  for (int i = threadIdx.x; i < DIM * 8; i += 256) s[i] = cw[i];
  __syncthreads();
  int n = blockIdx.x * 256 + threadIdx.x;
  if (n >= N_NODES) return;
  float acc[8] = {0.f, 0.f, 0.f, 0.f, 0.f, 0.f, 0.f, 0.f};
  const float* hr = h + (size_t)n * DIM;
  for (int k4 = 0; k4 < 25; ++k4) {
    float4 v = *(const float4*)(hr + k4 * 4);
    float vv[4] = {v.x, v.y, v.z, v.w};
#pragma unroll
    for (int kk = 0; kk < 4; ++kk) {
      const float* sr = s + (k4 * 4 + kk) * 8;
#pragma unroll
      for (int c = 0; c < 8; ++c) acc[c] += vv[kk] * sr[c];
    }
  }
  *(float4*)(sc_i + (size_t)n * 4) = make_float4(acc[0], acc[1], acc[2], acc[3]);
  *(float4*)(sc_j + (size_t)n * 4) = make_float4(acc[4], acc[5], acc[6], acc[7]);
}

#define ALPHA_P(pp)                                                                  \
  int s_ = csr_src[pp];                                                              \
  float4 sj_ = *(const float4*)(sc_j + (size_t)s_ * 4);                              \
  ushort4 eb_ = *(const ushort4*)(esc_l + (size_t)(pp) * 4);                         \
  float a0 = si.x + sj_.x + h2f(eb_.x); a0 = a0 > 0.f ? a0 : 0.2f * a0;              \
  float a1 = si.y + sj_.y + h2f(eb_.y); a1 = a1 > 0.f ? a1 : 0.2f * a1;              \
  float a2 = si.z + sj_.z + h2f(eb_.z); a2 = a2 > 0.f ? a2 : 0.2f * a2;              \
  float a3 = si.w + sj_.w + h2f(eb_.w); a3 = a3 > 0.f ? a3 : 0.2f * a3;

// 4 nodes per WAVE (16 per block): segment softmax per node (sequential),
// then one interleaved gather loop issuing all 4 nodes' h-row loads per
// iteration -> 4x memory-level parallelism on the latency-bound h gather.
// Per-node fma order identical to the 1-node version (bitwise-same results).
__global__ __launch_bounds__(256) void k_aggr(const float* __restrict__ h,
                                              const float* __restrict__ sc_i,
                                              const float* __restrict__ sc_j,
                                              const unsigned short* __restrict__ esc_l,
                                              const int* __restrict__ indptr,
                                              const int* __restrict__ csr_src,
                                              unsigned short* __restrict__ agg2h) {
  __shared__ __align__(16) uint4 s_pack[4][4][64];   // 16 KB: [wave][r][lane]
  int wave = threadIdx.x >> 6;
  int lane = threadIdx.x & 63;
  int nb = (blockIdx.x * 4 + wave) * 4;           // wave's 4 nodes; 1875*16=30000
  bool has2 = lane < (DIM - 64);

  float A0[4], A1[4], A2[4], A3[4];
  float C0[4], C1[4], C2[4], C3[4];
  int degf[4];

#pragma unroll
  for (int r = 0; r < 4; ++r) {
    int n = nb + r;
    int start = indptr[n], end = indptr[n + 1];
    int deg = end - start;
    float4 si = *(const float4*)(sc_i + (size_t)n * 4);
    A0[r] = A1[r] = A2[r] = A3[r] = 0.f;
    C0[r] = C1[r] = C2[r] = C3[r] = 0.f;

    if (deg <= 64) {
      // ---- fast path: one edge per lane, single alpha computation ----
      int p = start + lane;
      bool act = p < end;
      int srcr = 0;
      float a0 = -1e30f, a1 = -1e30f, a2 = -1e30f, a3 = -1e30f;
      if (act) {
        int s2 = csr_src[p];
        float4 sj2 = *(const float4*)(sc_j + (size_t)s2 * 4);
        ushort4 eb2 = *(const ushort4*)(esc_l + (size_t)p * 4);
        a0 = si.x + sj2.x + h2f(eb2.x); a0 = a0 > 0.f ? a0 : 0.2f * a0;
        a1 = si.y + sj2.y + h2f(eb2.y); a1 = a1 > 0.f ? a1 : 0.2f * a1;
        a2 = si.z + sj2.z + h2f(eb2.z); a2 = a2 > 0.f ? a2 : 0.2f * a2;
        a3 = si.w + sj2.w + h2f(eb2.w); a3 = a3 > 0.f ? a3 : 0.2f * a3;
        srcr = s2;
      }
      float m0 = a0, m1 = a1, m2 = a2, m3 = a3;
      for (int off = 32; off; off >>= 1) {
        m0 = fmaxf(m0, __shfl_xor(m0, off));
        m1 = fmaxf(m1, __shfl_xor(m1, off));
        m2 = fmaxf(m2, __shfl_xor(m2, off));
        m3 = fmaxf(m3, __shfl_xor(m3, off));
      }
      float e0 = act ? __expf(a0 - m0) : 0.f;
      float e1 = act ? __expf(a1 - m1) : 0.f;
      float e2 = act ? __expf(a2 - m2) : 0.f;
      float e3 = act ? __expf(a3 - m3) : 0.f;
      float d0 = e0, d1 = e1, d2 = e2, d3 = e3;
      for (int off = 32; off; off >>= 1) {
        d0 += __shfl_xor(d0, off); d1 += __shfl_xor(d1, off);
        d2 += __shfl_xor(d2, off); d3 += __shfl_xor(d3, off);
      }
      float w0 = e0 * (1.f / (d0 + 1e-16f));
      float w1 = e1 * (1.f / (d1 + 1e-16f));
      float w2 = e2 * (1.f / (d2 + 1e-16f));
      float w3 = e3 * (1.f / (d3 + 1e-16f));
      uint4 pk;
      pk.x = (unsigned)srcr;
      pk.y = (unsigned)f2h(w0) | ((unsigned)f2h(w1) << 16);
      pk.z = (unsigned)f2h(w2) | ((unsigned)f2h(w3) << 16);
      pk.w = 0u;
      s_pack[wave][r][lane] = pk;   // wave-synchronous
      degf[r] = deg;
    } else {
      // ---- generic path (deg > 64): 3-pass recompute; rare. Writes own row.
      degf[r] = 0;
      float m0 = -1e30f, m1 = -1e30f, m2 = -1e30f, m3 = -1e30f;
      for (int p = start + lane; p < end; p += 64) {
        ALPHA_P(p)
        (void)s_;
        m0 = fmaxf(m0, a0); m1 = fmaxf(m1, a1); m2 = fmaxf(m2, a2); m3 = fmaxf(m3, a3);
      }
      for (int off = 32; off; off >>= 1) {
        m0 = fmaxf(m0, __shfl_xor(m0, off));
        m1 = fmaxf(m1, __shfl_xor(m1, off));
        m2 = fmaxf(m2, __shfl_xor(m2, off));
        m3 = fmaxf(m3, __shfl_xor(m3, off));
      }
      float d0 = 0.f, d1 = 0.f, d2 = 0.f, d3 = 0.f;
      for (int p = start + lane; p < end; p += 64) {
        ALPHA_P(p)
        (void)s_;
        d0 += __expf(a0 - m0); d1 += __expf(a1 - m1);
        d2 += __expf(a2 - m2); d3 += __expf(a3 - m3);
      }
      for (int off = 32; off; off >>= 1) {
        d0 += __shfl_xor(d0, off); d1 += __shfl_xor(d1, off);
        d2 += __shfl_xor(d2, off); d3 += __shfl_xor(d3, off);
      }
      float i0 = 1.f / (d0 + 1e-16f), i1 = 1.f / (d1 + 1e-16f);
      float i2 = 1.f / (d2 + 1e-16f), i3 = 1.f / (d3 + 1e-16f);
      float gA0 = 0.f, gA1 = 0.f, gA2 = 0.f, gA3 = 0.f;
      float gB0 = 0.f, gB1 = 0.f, gB2 = 0.f, gB3 = 0.f;
      for (int base = start; base < end; base += 64) {
        int cntv = min(64, end - base);
        int p = base + lane;
        float w0 = 0.f, w1 = 0.f, w2 = 0.f, w3 = 0.f;
        int srcr = 0;
        if (p < end) {
          ALPHA_P(p)
          w0 = __expf(a0 - m0) * i0; w1 = __expf(a1 - m1) * i1;
          w2 = __expf(a2 - m2) * i2; w3 = __expf(a3 - m3) * i3;
          srcr = s_;
        }
        for (int j = 0; j < cntv; ++j) {
          int sj2 = __shfl(srcr, j);
          float q0 = __shfl(w0, j), q1 = __shfl(w1, j);
          float q2 = __shfl(w2, j), q3 = __shfl(w3, j);
          const float* hr = h + (size_t)sj2 * DIM;
          float hv0 = hr[lane];
          float hv1 = has2 ? hr[64 + lane] : 0.f;
          gA0 += q0 * hv0; gA1 += q1 * hv0; gA2 += q2 * hv0; gA3 += q3 * hv0;
          gB0 += q0 * hv1; gB1 += q1 * hv1; gB2 += q2 * hv1; gB3 += q3 * hv1;
        }
      }
      unsigned short* outp = agg2h + (size_t)n * KP;
      outp[lane] = f2h(gA0); outp[100 + lane] = f2h(gA1);
      outp[200 + lane] = f2h(gA2); outp[300 + lane] = f2h(gA3);
      if (has2) {
        outp[64 + lane] = f2h(gB0); outp[164 + lane] = f2h(gB1);
        outp[264 + lane] = f2h(gB2); outp[364 + lane] = f2h(gB3);
      }
      if (lane < KP - 400) outp[400 + lane] = 0;
    }
  }

  // ---- interleaved gather loop: 4 nodes' edge j processed per iteration ----
  int dmax = max(max(degf[0], degf[1]), max(degf[2], degf[3]));
  for (int j = 0; j < dmax; ++j) {
#pragma unroll
    for (int r = 0; r < 4; ++r) {
      if (j < degf[r]) {            // wave-uniform branch
        uint4 pk2 = s_pack[wave][r][j];     // broadcast read
        int sj2 = (int)pk2.x;
        float q0 = h2f((unsigned short)(pk2.y & 0xffffu));
        float q1 = h2f((unsigned short)(pk2.y >> 16));
        float q2 = h2f((unsigned short)(pk2.z & 0xffffu));
        float q3 = h2f((unsigned short)(pk2.z >> 16));
        const float* hr = h + (size_t)sj2 * DIM;
        float hv0 = hr[lane];
        float hv1 = has2 ? hr[64 + lane] : 0.f;
        A0[r] += q0 * hv0; A1[r] += q1 * hv0; A2[r] += q2 * hv0; A3[r] += q3 * hv0;
        C0[r] += q0 * hv1; C1[r] += q1 * hv1; C2[r] += q2 * hv1; C3[r] += q3 * hv1;
      }
    }
  }

#pragma unroll
  for (int r = 0; r < 4; ++r) {
    if (degf[r] > 0) {
      unsigned short* outp = agg2h + (size_t)(nb + r) * KP;
      outp[lane] = f2h(A0[r]); outp[100 + lane] = f2h(A1[r]);
      outp[200 + lane] = f2h(A2[r]); outp[300 + lane] = f2h(A3[r]);
      if (has2) {
        outp[64 + lane] = f2h(C0[r]); outp[164 + lane] = f2h(C1[r]);
        outp[264 + lane] = f2h(C2[r]); outp[364 + lane] = f2h(C3[r]);
      }
      if (lane < KP - 400) outp[400 + lane] = 0;   // zero K-pad for MFMA
    }
  }
}

// GEMM2 via MFMA f16: C[30000,100] = agg2h[30000,416] @ B[416,112(pad)]
// No LDS. Wave = 16 rows x 7 col-tiles; A-frag 16B coalesced loads, B-frag
// pre-packed in operand order. Fused LayerNorm + ELU + residual epilogue.
__global__ __launch_bounds__(256) void k_gemm2(const _Float16* __restrict__ agg2h,
                                               const _Float16* __restrict__ Bfrag_l,
                                               const float* __restrict__ lg,
                                               const float* __restrict__ lb,
                                               float* __restrict__ h) {
  int t = threadIdx.x;
  int lane = t & 63;
  int w = t >> 6;
  int c = lane & 15;        // col within tile / A-row within tile
  int quad = lane >> 4;
  int nb = blockIdx.x * 64 + w * 16;     // wave's 16 rows

  f32x4 acc[7];
#pragma unroll
  for (int ct = 0; ct < 7; ++ct) acc[ct] = (f32x4){0.f, 0.f, 0.f, 0.f};

  const _Float16* arow = agg2h + (size_t)(nb + c) * KP + quad * 8;
#pragma unroll
  for (int ks = 0; ks < 13; ++ks) {
    half8 a = *(const half8*)(arow + ks * 32);
    const _Float16* bp = Bfrag_l + (size_t)(ks * 64 + lane) * 8;
#pragma unroll
    for (int ct = 0; ct < 7; ++ct) {
      half8 b = *(const half8*)(bp + (size_t)ct * 13 * 64 * 8);
      acc[ct] = __builtin_amdgcn_mfma_f32_16x16x32_f16(a, b, acc[ct], 0, 0, 0);
    }
  }

  // epilogue: C/D layout col=lane&15, row=quad*4+reg. LN across the 16 lanes
  // of a quad (xor 1,2,4,8 stays inside the 16-lane group).
  float gv[7], bv[7];
#pragma unroll
  for (int ct = 0; ct < 7; ++ct) {
    int col = ct * 16 + c;
    gv[ct] = (col < DIM) ? lg[col] : 0.f;
    bv[ct] = (col < DIM) ? lb[col] : 0.f;
  }
  bool c4 = c < 4;   // ct=6 valid cols: 96..99
#pragma unroll
  for (int r = 0; r < 4; ++r) {
    int n = nb + quad * 4 + r;
    float v[7];
#pragma unroll
    for (int ct = 0; ct < 7; ++ct) v[ct] = acc[ct][r];
    float s = v[0] + v[1] + v[2] + v[3] + v[4] + v[5] + (c4 ? v[6] : 0.f);
    s += __shfl_xor(s, 1); s += __shfl_xor(s, 2);
    s += __shfl_xor(s, 4); s += __shfl_xor(s, 8);
    float mu = s * 0.01f;
    float dv[7];
    float s2 = 0.f;
#pragma unroll
    for (int ct = 0; ct < 6; ++ct) { dv[ct] = v[ct] - mu; s2 += dv[ct] * dv[ct]; }
    dv[6] = c4 ? (v[6] - mu) : 0.f;
    s2 += dv[6] * dv[6];
    s2 += __shfl_xor(s2, 1); s2 += __shfl_xor(s2, 2);
    s2 += __shfl_xor(s2, 4); s2 += __shfl_xor(s2, 8);
    float rstd = rsqrtf(s2 * 0.01f + 1e-5f);
    if (n < N_NODES) {
      float* hp = h + (size_t)n * DIM;
#pragma unroll
      for (int ct = 0; ct < 7; ++ct) {
        int col = ct * 16 + c;
        if (ct < 6 || c4) {
          float y = dv[ct] * rstd * gv[ct] + bv[ct];
          y = y > 0.f ? y : (__expf(y) - 1.f);
          hp[col] += y;
        }
      }
    }
  }
}

// pool via run-length accumulation (batch is sorted): ~2 atomics/dim/block
__global__ __launch_bounds__(128) void k_pool(const float* __restrict__ h,
                                              const int* __restrict__ batch,
                                              float* __restrict__ pooled, float* __restrict__ cnt) {
  int d = threadIdx.x;
  int n0 = blockIdx.x * 64;
  int n1 = min(n0 + 64, N_NODES);
  if (n0 >= N_NODES) return;
  int curg = -1;
  float acc = 0.f, c = 0.f;
  for (int n = n0; n < n1; ++n) {
    int g = batch[n];
    if (g != curg) {
      if (curg >= 0) {
        if (d < 100) atomicAdd(&pooled[(size_t)curg * DIM + d], acc);
        if (d == 0) atomicAdd(&cnt[curg], c);
      }
      curg = g; acc = 0.f; c = 0.f;
    }
    if (d < 100) acc += h[(size_t)n * DIM + d];
    c += 1.f;
  }
  if (curg >= 0) {
    if (d < 100) atomicAdd(&pooled[(size_t)curg * DIM + d], acc);
    if (d == 0) atomicAdd(&cnt[curg], c);
  }
}

__global__ __launch_bounds__(64) void k_mlp(const float* __restrict__ pooled,
                                            const float* __restrict__ cnt,
                                            const float* __restrict__ w1, const float* __restrict__ b1,
                                            const float* __restrict__ w2, const float* __restrict__ b2,
                                            float* __restrict__ out) {
  int g = blockIdx.x;
  int j = threadIdx.x;
  float invc = 1.0f / fmaxf(cnt[g], 1.0f);
  const float* pr = pooled + (size_t)g * DIM;
  const float* wr = w1 + (size_t)j * DIM;
  float acc = 0.f;
  for (int k = 0; k < DIM; ++k) acc += pr[k] * wr[k];
  float hh = acc * invc + b1[j];
  out[NG + g * 64 + j] = hh;
  float v = hh * w2[j];
  for (int off = 32; off; off >>= 1) v += __shfl_xor(v, off);
  if (j == 0) out[g] = v + b2[0];
}

// ---------------------------------------------------------------------------
extern "C" void kernel_launch(void* const* d_in, const int* in_sizes, int n_in,
                              void* d_out, int out_size, void* d_ws, size_t ws_size,
                              hipStream_t stream) {
  (void)in_sizes; (void)n_in; (void)out_size; (void)ws_size;
  const int* x = (const int*)d_in[0];
  const int* ei = (const int*)d_in[1];
  const float* ea = (const float*)d_in[2];
  const int* batch = (const int*)d_in[3];
  const float* emb = (const float*)d_in[4];
  const float* W = (const float*)d_in[5];
  const float* We = (const float*)d_in[6];
  const float* a = (const float*)d_in[7];
  const float* ln_g = (const float*)d_in[8];
  const float* ln_b = (const float*)d_in[9];
  const float* w1 = (const float*)d_in[10];
  const float* b1 = (const float*)d_in[11];
  const float* w2 = (const float*)d_in[12];
  const float* b2 = (const float*)d_in[13];
  float* outp = (float*)d_out;

  char* ws = (char*)d_ws;
  float* h = (float*)(ws + OFF_H);
  unsigned short* agg2h = (unsigned short*)(ws + OFF_AGG2);
  int* csr_eid = (int*)(ws + OFF_EID);
  int* deg = (int*)(ws + OFF_DEG);
  int* cursor = (int*)(ws + OFF_CURS);
  unsigned short* esc_tmp = (unsigned short*)(ws + OFF_ETMP);
  float* pooled = (float*)(ws + OFF_POOL);
  float* cnt = (float*)(ws + OFF_CNT);
  float* sc_i = (float*)(ws + OFF_SCI);
  float* sc_j = (float*)(ws + OFF_SCJ);
  unsigned short* esc = (unsigned short*)(ws + OFF_ESC);
  float* cWij = (float*)(ws + OFF_CWIJ);
  unsigned short* Bw = (unsigned short*)(ws + OFF_BW);
  unsigned short* Bfrag = (unsigned short*)(ws + OFF_WR);
  int* indptr = (int*)(ws + OFF_INDPTR);
  int* csr_src = (int*)(ws + OFF_CSRS);
  int* bsum = (int*)(ws + OFF_BSUM);

  k_init<<<11719, 256, 0, stream>>>(x, emb, h, deg, cursor);
  k_fold<<<61, 256, 0, stream>>>(W, We, a, cWij, Bw);
  k_bfrag<<<1092, 256, 0, stream>>>(W, Bfrag);
  k_deg<<<1993, 256, 0, stream>>>(ei, deg);
  k_scan1<<<30, 1024, 0, stream>>>(deg, indptr, bsum);
  k_scan2<<<1, 64, 0, stream>>>(bsum);
  k_scan3<<<30, 1024, 0, stream>>>(indptr, bsum);
  k_scatter<<<1993, 256, 0, stream>>>(ei, indptr, cursor, csr_src, csr_eid);
  k_escore<<<7500, 256, 0, stream>>>(ea, Bw, esc_tmp);
  k_permute<<<1993, 256, 0, stream>>>(esc_tmp, csr_eid, esc);

  for (int l = 0; l < NL; ++l) {
    k_score<<<118, 256, 0, stream>>>(h, cWij + l * 800, sc_i, sc_j);
    k_aggr<<<1875, 256, 0, stream>>>(h, sc_i, sc_j, esc + (size_t)l * EP_EDGES * 4,
                                     indptr, csr_src, agg2h);
    k_gemm2<<<469, 256, 0, stream>>>((const _Float16*)agg2h,
                                     (const _Float16*)(Bfrag + (size_t)l * 7 * 13 * 64 * 8),
                                     ln_g + l * 100, ln_b + l * 100, h);
  }

  hipMemsetAsync(ws + OFF_POOL, 0, 51200 + 512, stream);
  k_pool<<<469, 128, 0, stream>>>(h, batch, pooled, cnt);
  k_mlp<<<128, 64, 0, stream>>>(pooled, cnt, w1, b1, w2, b2, outp);
}

// Round 7
// 877.293 us; speedup vs baseline: 1.0872x; 1.0872x over previous
//
#include <hip/hip_runtime.h>
#include <cstdint>
#include <cstddef>

#define N_NODES 30000
#define N_EDGES 480000
#define EP_EDGES (N_EDGES + N_NODES)   // 510000, with self-loops appended
#define DIM 100
#define NH 4
#define NL 6
#define NG 128
#define KP 416                         // GEMM2 K padded to 13*32

// ---------------------------------------------------------------------------
// Workspace layout (bytes). Peak ~88.6 MB (known-good bound: 112.5 MB).
#define OFF_H       0u            // float [30000][100]
#define OFF_AGG2    12000000u     // fp16  [30000][416]  (24.96 MB, loop only)
#define OFF_EID     12000000u     // int   [510000]   (overlay, pre-loop: csr slot -> edge id, -1=self-loop)
#define OFF_DEG     14040000u     // int   [30000]    (overlay, pre-loop)
#define OFF_CURS    14160000u     // int   [30000]    (overlay, pre-loop)
#define OFF_ETMP    16000000u     // fp16  [480000][24] edge-order scores (overlay, pre-loop, 23.04 MB)
#define OFF_POOL    12000000u     // float [128][100] (overlay, post-loop)
#define OFF_CNT     12051200u     // float [128]      (overlay, post-loop)
#define OFF_SCI     60000000u     // float [30000][4]
#define OFF_SCJ     60480000u     // float [30000][4]
#define OFF_ESC     60960000u     // fp16  [6][510000][4]  (CSR order!)
#define OFF_CWIJ    85440000u     // float [6][100][8]  (c = isJ*4 + h)
#define OFF_WR      85469184u     // fp16  Bfrag [6][7][13][64][8]  (559 KB)
#define OFF_INDPTR  86429184u     // int   [30001]
#define OFF_CSRS    86549248u     // int   [510000]
#define OFF_BSUM    88589248u     // int   [32]
#define OFF_BW      88589376u     // fp16  Bw [2(hl)][2(ct)][4(ks)][64][8]  (16 KB, escore MFMA B)

typedef _Float16 half8 __attribute__((ext_vector_type(8)));
typedef __fp16 fp16x2 __attribute__((ext_vector_type(2)));
typedef float f32x4 __attribute__((ext_vector_type(4)));

static __device__ __forceinline__ unsigned short f2h(float f) {
  return __builtin_bit_cast(unsigned short, (_Float16)f);
}
static __device__ __forceinline__ float h2f(unsigned short u) {
  return (float)__builtin_bit_cast(_Float16, u);
}

// ---------------------------------------------------------------------------
__global__ __launch_bounds__(256) void k_init(const int* __restrict__ x,
                                              const float* __restrict__ emb,
                                              float* __restrict__ h,
                                              int* __restrict__ deg, int* __restrict__ cursor) {
  int tid = blockIdx.x * 256 + threadIdx.x;
  if (tid < N_NODES * DIM) {
    int n = tid / DIM;
    int d = tid - n * DIM;
    h[tid] = emb[x[n] * DIM + d];
  }
  if (tid < N_NODES) { deg[tid] = 0; cursor[tid] = 0; }
}

// fold W,We with a_i/a_j:
//  - cWij[l][k][c] (c=isJ*4+h)  for k_score
//  - Bw: escore MFMA B-operand, split precision (hl=0: f16(v), hl=1: f16(v-f32(f16(v)))).
//    Entry (hl,ct,ks,lane,j) = folded We.a_j for col c=ct*16+(lane&15) (=l*4+h),
//    k = ks*32 + (lane>>4)*8 + j; zero outside c<24 || k<100.
__global__ __launch_bounds__(256) void k_fold(const float* __restrict__ W,
                                              const float* __restrict__ We,
                                              const float* __restrict__ a,
                                              float* __restrict__ cWij,
                                              unsigned short* __restrict__ Bw) {
  int tid = blockIdx.x * 256 + threadIdx.x;
  if (tid < NL * DIM * 8) {
    int l = tid / 800, r = tid % 800;
    int k = r >> 3, c = r & 7;
    int hh = c & 3, isJ = c >> 2;
    const float* wp = W + (size_t)(l * 400 + hh * 100) * 100 + k;
    const float* ap = a + (size_t)(l * 4 + hh) * 200 + isJ * 100;
    float s = 0.f;
    for (int d = 0; d < 100; ++d) s += wp[(size_t)d * 100] * ap[d];
    cWij[l * 800 + k * 8 + c] = s;
  } else if (tid < NL * DIM * 8 + DIM * 24) {
    int m = tid - NL * DIM * 8;
    int k = m / 24, c = m % 24;
    int l = c >> 2, hh = c & 3;
    const float* wp = We + (size_t)(l * 400 + hh * 100) * 100 + k;
    const float* ap = a + (size_t)(l * 4 + hh) * 200 + 100;
    float s = 0.f;
    for (int d = 0; d < 100; ++d) s += wp[(size_t)d * 100] * ap[d];
    // split precision + scatter into MFMA B-operand order
    _Float16 vh = (_Float16)s;
    _Float16 vl = (_Float16)(s - (float)vh);
    int ct = c >> 4;
    int lane = (((k & 31) >> 3) << 4) | (c & 15);
    int ks = k >> 5;
    int j = k & 7;
    Bw[(size_t)(((0 * 2 + ct) * 4 + ks) * 64 + lane) * 8 + j] = __builtin_bit_cast(unsigned short, vh);
    Bw[(size_t)(((1 * 2 + ct) * 4 + ks) * 64 + lane) * 8 + j] = __builtin_bit_cast(unsigned short, vl);
  } else if (tid < NL * DIM * 8 + DIM * 24 + 8192) {
    // zero-fill the invalid (padding) Bw entries; disjoint from valid writes.
    int E = tid - (NL * DIM * 8 + DIM * 24);
    int j = E & 7;
    int lane = (E >> 3) & 63;
    int rest = E >> 9;          // [0,16)
    int ks = rest & 3;
    int ct = (rest >> 2) & 1;
    int c = ct * 16 + (lane & 15);
    int k = ks * 32 + ((lane >> 4) << 3) + j;
    if (!(c < 24 && k < 100)) Bw[E] = 0;
  }
}

// Bfrag[l][ct][ks][lane][j] (f16) = B[k][n] in MFMA B-operand order:
//   k = ks*32 + (lane>>4)*8 + j,  n = ct*16 + (lane&15)
//   B[k=hh*100+kk][n] = W[l][hh*100 + n][kk]   (zeros in pads)
__global__ __launch_bounds__(256) void k_bfrag(const float* __restrict__ W,
                                               unsigned short* __restrict__ Bfrag) {
  int tid = blockIdx.x * 256 + threadIdx.x;
  if (tid >= NL * 7 * 13 * 64 * 8) return;
  int j = tid & 7;
  int lane = (tid >> 3) & 63;
  int rest = tid >> 9;          // ((l*7+ct)*13+ks)
  int ks = rest % 13;
  int rest2 = rest / 13;
  int ct = rest2 % 7;
  int l = rest2 / 7;
  int k = ks * 32 + ((lane >> 4) << 3) + j;
  int n = ct * 16 + (lane & 15);
  float v = 0.f;
  if (k < 400 && n < 100) {
    int hh = k / 100, kk = k - hh * 100;
    v = W[(size_t)(l * 400 + hh * 100 + n) * 100 + kk];
  }
  Bfrag[tid] = f2h(v);
}

__global__ __launch_bounds__(256) void k_deg(const int* __restrict__ ei, int* __restrict__ deg) {
  int tid = blockIdx.x * 256 + threadIdx.x;
  if (tid >= EP_EDGES) return;
  int dstn = (tid < N_EDGES) ? ei[N_EDGES + tid] : (tid - N_EDGES);
  atomicAdd(&deg[dstn], 1);
}

// two-level scan: per-block inclusive scan (30 blocks x 1024)
__global__ __launch_bounds__(1024) void k_scan1(const int* __restrict__ deg,
                                                int* __restrict__ indptr, int* __restrict__ bsum) {
  __shared__ int s[1024];
  int t = threadIdx.x;
  int i = blockIdx.x * 1024 + t;
  int v = (i < N_NODES) ? deg[i] : 0;
  s[t] = v;
  __syncthreads();
  for (int off = 1; off < 1024; off <<= 1) {
    int tmp = (t >= off) ? s[t - off] : 0;
    __syncthreads();
    s[t] += tmp;
    __syncthreads();
  }
  if (i < N_NODES) indptr[i + 1] = s[t];
  if (t == 1023) bsum[blockIdx.x] = s[1023];
}
// scan 30 block sums -> exclusive offsets (1 wave)
__global__ __launch_bounds__(64) void k_scan2(int* __restrict__ bsum) {
  int t = threadIdx.x;
  int v = (t < 30) ? bsum[t] : 0;
  int inc = v;
  for (int off = 1; off < 64; off <<= 1) {
    int up = __shfl_up(inc, off);
    if (t >= off) inc += up;
  }
  if (t < 30) bsum[t] = inc - v;   // exclusive
}
__global__ __launch_bounds__(1024) void k_scan3(int* __restrict__ indptr,
                                                const int* __restrict__ bsum) {
  int i = blockIdx.x * 1024 + threadIdx.x;
  if (i < N_NODES) indptr[i + 1] += bsum[blockIdx.x];
  if (i == 0) indptr[0] = 0;
}

// build CSR; record inverse permutation csr_eid[p] = edge id (-1 for self-loop)
__global__ __launch_bounds__(256) void k_scatter(const int* __restrict__ ei,
                                                 const int* __restrict__ indptr,
                                                 int* __restrict__ cursor,
                                                 int* __restrict__ csr_src,
                                                 int* __restrict__ csr_eid) {
  int tid = blockIdx.x * 256 + threadIdx.x;
  if (tid >= EP_EDGES) return;
  int dstn = (tid < N_EDGES) ? ei[N_EDGES + tid] : (tid - N_EDGES);
  int srcn = (tid < N_EDGES) ? ei[tid] : (tid - N_EDGES);
  int p = indptr[dstn] + atomicAdd(&cursor[dstn], 1);
  csr_src[p] = srcn;
  csr_eid[p] = (tid < N_EDGES) ? tid : -1;
}

// esc_tmp[e][l*4+h] = fp16( edge_attr[e,:] . cWe[l*4+h,:] ), EDGE order, via
// MFMA 16x16x32 f16 with split-precision compensation:
//   score = xh@wh + xl@wh + xh@wl   (residual ~2^-20 rel; f32-equivalent)
// B-operand (weights, 16 half8) lives in VGPRs for the whole kernel.
// A: 64 edge rows staged f32 into XOR-swizzled LDS (conflict-free b128 reads),
// hi/lo split on the fly. One-shot blocks: 7500 x 256 (4 waves, wave = 16 rows).
__global__ __launch_bounds__(256, 4) void k_escore(const float* __restrict__ ea,
                                                   const unsigned short* __restrict__ Bw,
                                                   unsigned short* __restrict__ esc_tmp) {
  __shared__ __align__(16) float s_ea[64 * 128];   // 32 KB, [row][128 f32], swizzled
  int t = threadIdx.x;
  int lane = t & 63;
  int wv = t >> 6;

  // ---- B fragments: load once, keep in VGPRs (16 half8 = 64 VGPRs) ----
  const half8* bp = (const half8*)Bw;
  half8 Bh[2][4], Bl[2][4];
#pragma unroll
  for (int ct = 0; ct < 2; ++ct)
#pragma unroll
    for (int ks = 0; ks < 4; ++ks) {
      Bh[ct][ks] = bp[((0 * 2 + ct) * 4 + ks) * 64 + lane];
      Bl[ct][ks] = bp[((1 * 2 + ct) * 4 + ks) * 64 + lane];
    }

  // ---- stage tile: zero K-pad chunks + 64 rows x 25 float4, swizzled ----
  int e0 = blockIdx.x * 64;
  const float4* g4 = (const float4*)(ea + (size_t)e0 * 100);
  for (int z = t; z < 448; z += 256) {          // rows x chunks 25..31 (k 100..127)
    int zr = z / 7, zc = z - zr * 7;
    int o = 400 + zc * 16;
    *(float4*)((char*)s_ea + zr * 512 + (o ^ ((zr & 7) << 4))) = (float4){0.f, 0.f, 0.f, 0.f};
  }
#pragma unroll
  for (int i = 0; i < 7; ++i) {
    int v = i * 256 + t;
    if (i < 6 || v < 1600) {
      float4 val = g4[v];
      int r = v / 25, kk = v - r * 25;
      *(float4*)((char*)s_ea + r * 512 + ((kk * 16) ^ ((r & 7) << 4))) = val;
    }
  }
  __syncthreads();

  // ---- MFMA main: wave wv handles edge rows wv*16 .. +15 ----
  int c = lane & 15;
  int quad = lane >> 4;
  int lrow = wv * 16 + c;                 // A-operand row for this lane
  int swz = (lrow & 7) << 4;
  const char* base = (const char*)s_ea + lrow * 512;
  f32x4 acc0 = (f32x4){0.f, 0.f, 0.f, 0.f};
  f32x4 acc1 = (f32x4){0.f, 0.f, 0.f, 0.f};
#pragma unroll
  for (int ks = 0; ks < 4; ++ks) {
    int o = ks * 128 + quad * 32;
    float4 xa = *(const float4*)(base + ((o) ^ swz));
    float4 xb = *(const float4*)(base + ((o + 16) ^ swz));
    fp16x2 h0 = __builtin_amdgcn_cvt_pkrtz(xa.x, xa.y);
    fp16x2 h1 = __builtin_amdgcn_cvt_pkrtz(xa.z, xa.w);
    fp16x2 h2 = __builtin_amdgcn_cvt_pkrtz(xb.x, xb.y);
    fp16x2 h3 = __builtin_amdgcn_cvt_pkrtz(xb.z, xb.w);
    fp16x2 l0 = __builtin_amdgcn_cvt_pkrtz(xa.x - (float)h0[0], xa.y - (float)h0[1]);
    fp16x2 l1 = __builtin_amdgcn_cvt_pkrtz(xa.z - (float)h1[0], xa.w - (float)h1[1]);
    fp16x2 l2 = __builtin_amdgcn_cvt_pkrtz(xb.x - (float)h2[0], xb.y - (float)h2[1]);
    fp16x2 l3 = __builtin_amdgcn_cvt_pkrtz(xb.z - (float)h3[0], xb.w - (float)h3[1]);
    uint4 uh = {__builtin_bit_cast(unsigned, h0), __builtin_bit_cast(unsigned, h1),
                __builtin_bit_cast(unsigned, h2), __builtin_bit_cast(unsigned, h3)};
    uint4 ul = {__builtin_bit_cast(unsigned, l0), __builtin_bit_cast(unsigned, l1),
                __builtin_bit_cast(unsigned, l2), __builtin_bit_cast(unsigned, l3)};
    half8 xh = __builtin_bit_cast(half8, uh);
    half8 xl = __builtin_bit_cast(half8, ul);
    acc0 = __builtin_amdgcn_mfma_f32_16x16x32_f16(xh, Bh[0][ks], acc0, 0, 0, 0);
    acc0 = __builtin_amdgcn_mfma_f32_16x16x32_f16(xl, Bh[0][ks], acc0, 0, 0, 0);
    acc0 = __builtin_amdgcn_mfma_f32_16x16x32_f16(xh, Bl[0][ks], acc0, 0, 0, 0);
    acc1 = __builtin_amdgcn_mfma_f32_16x16x32_f16(xh, Bh[1][ks], acc1, 0, 0, 0);
    acc1 = __builtin_amdgcn_mfma_f32_16x16x32_f16(xl, Bh[1][ks], acc1, 0, 0, 0);
    acc1 = __builtin_amdgcn_mfma_f32_16x16x32_f16(xh, Bl[1][ks], acc1, 0, 0, 0);
  }

  // ---- epilogue: C/D col=lane&15, row=quad*4+r. cols: ct0 -> c, ct1 -> 16+c ----
  unsigned short* orow = esc_tmp + (size_t)(e0 + wv * 16 + quad * 4) * 24;
#pragma unroll
  for (int r = 0; r < 4; ++r) {
    unsigned short* op = orow + r * 24;
    op[c] = f2h(acc0[r]);
    if (c < 8) op[16 + c] = f2h(acc1[r]);
  }
}

// permute edge-order scores into CSR order, all 6 layers per slot.
// Random 48B (one line) read per real edge; fully coalesced 6x8B writes.
// Self-loop slots (eid = -1) write zeros.
__global__ __launch_bounds__(256) void k_permute(const unsigned short* __restrict__ esc_tmp,
                                                 const int* __restrict__ csr_eid,
                                                 unsigned short* __restrict__ esc) {
  int p = blockIdx.x * 256 + threadIdx.x;
  if (p >= EP_EDGES) return;
  int e = csr_eid[p];
  ushort4 v[NL];
  if (e >= 0) {
    const unsigned short* rp = esc_tmp + (size_t)e * 24;
#pragma unroll
    for (int l = 0; l < NL; ++l) v[l] = *(const ushort4*)(rp + l * 4);
  } else {
#pragma unroll
    for (int l = 0; l < NL; ++l) { v[l].x = 0; v[l].y = 0; v[l].z = 0; v[l].w = 0; }
  }
#pragma unroll
  for (int l = 0; l < NL; ++l)
    *(ushort4*)(esc + ((size_t)l * EP_EDGES + p) * 4) = v[l];
}

// per-node attention scores: sc_i[n,h], sc_j[n,h]
__global__ __launch_bounds__(256) void k_score(const float* __restrict__ h,
                                               const float* __restrict__ cw,  // [100][8]
                                               float* __restrict__ sc_i, float* __restrict__ sc_j) {
  __shared__ __align__(16) float s[DIM * 8];
  for (int i = threadIdx.x; i < DIM * 8; i += 256) s[i] = cw[i];
  __syncthreads();
  int n = blockIdx.x * 256 + threadIdx.x;
  if (n >= N_NODES) return;
  float acc[8] = {0.f, 0.f, 0.f, 0.f, 0.f, 0.f, 0.f, 0.f};
  const float* hr = h + (size_t)n * DIM;
  for (int k4 = 0; k4 < 25; ++k4) {
    float4 v = *(const float4*)(hr + k4 * 4);
    float vv[4] = {v.x, v.y, v.z, v.w};
#pragma unroll
    for (int kk = 0; kk < 4; ++kk) {
      const float* sr = s + (k4 * 4 + kk) * 8;
#pragma unroll
      for (int c = 0; c < 8; ++c) acc[c] += vv[kk] * sr[c];
    }
  }
  *(float4*)(sc_i + (size_t)n * 4) = make_float4(acc[0], acc[1], acc[2], acc[3]);
  *(float4*)(sc_j + (size_t)n * 4) = make_float4(acc[4], acc[5], acc[6], acc[7]);
}

#define ALPHA_P(pp)                                                                  \
  int s_ = csr_src[pp];                                                              \
  float4 sj_ = *(const float4*)(sc_j + (size_t)s_ * 4);                              \
  ushort4 eb_ = *(const ushort4*)(esc_l + (size_t)(pp) * 4);                         \
  float a0 = si.x + sj_.x + h2f(eb_.x); a0 = a0 > 0.f ? a0 : 0.2f * a0;              \
  float a1 = si.y + sj_.y + h2f(eb_.y); a1 = a1 > 0.f ? a1 : 0.2f * a1;              \
  float a2 = si.z + sj_.z + h2f(eb_.z); a2 = a2 > 0.f ? a2 : 0.2f * a2;              \
  float a3 = si.w + sj_.w + h2f(eb_.w); a3 = a3 > 0.f ? a3 : 0.2f * a3;

// one wave per node: segment softmax + weighted gather of h[src].
// The j-loop broadcasts (src, w) from lane j via v_readlane (scalar pipe,
// no LDS, no lgkmcnt) so the h-row loads issue back-to-back; #pragma unroll
// gives ~8 loads in flight per wave. Per-node fma order identical to the
// known-good version (bitwise-same results).
__global__ __launch_bounds__(256) void k_aggr(const float* __restrict__ h,
                                              const float* __restrict__ sc_i,
                                              const float* __restrict__ sc_j,
                                              const unsigned short* __restrict__ esc_l,
                                              const int* __restrict__ indptr,
                                              const int* __restrict__ csr_src,
                                              unsigned short* __restrict__ agg2h) {
  int wave = threadIdx.x >> 6;
  int lane = threadIdx.x & 63;
  int n = blockIdx.x * 4 + wave;                  // 7500*4 == 30000: no early-out
  int start = indptr[n], end = indptr[n + 1];
  int deg = end - start;
  float4 si = *(const float4*)(sc_i + (size_t)n * 4);
  float A0 = 0.f, A1 = 0.f, A2 = 0.f, A3 = 0.f;
  float B0 = 0.f, B1 = 0.f, B2 = 0.f, B3 = 0.f;
  bool has2 = lane < (DIM - 64);

  if (deg <= 64) {
    // ---- fast path: one edge per lane, single alpha computation ----
    int p = start + lane;
    bool act = p < end;
    int srcr = 0;
    float a0 = -1e30f, a1 = -1e30f, a2 = -1e30f, a3 = -1e30f;
    if (act) {
      int s2 = csr_src[p];
      float4 sj2 = *(const float4*)(sc_j + (size_t)s2 * 4);
      ushort4 eb2 = *(const ushort4*)(esc_l + (size_t)p * 4);
      a0 = si.x + sj2.x + h2f(eb2.x); a0 = a0 > 0.f ? a0 : 0.2f * a0;
      a1 = si.y + sj2.y + h2f(eb2.y); a1 = a1 > 0.f ? a1 : 0.2f * a1;
      a2 = si.z + sj2.z + h2f(eb2.z); a2 = a2 > 0.f ? a2 : 0.2f * a2;
      a3 = si.w + sj2.w + h2f(eb2.w); a3 = a3 > 0.f ? a3 : 0.2f * a3;
      srcr = s2;
    }
    float m0 = a0, m1 = a1, m2 = a2, m3 = a3;
    for (int off = 32; off; off >>= 1) {
      m0 = fmaxf(m0, __shfl_xor(m0, off));
      m1 = fmaxf(m1, __shfl_xor(m1, off));
      m2 = fmaxf(m2, __shfl_xor(m2, off));
      m3 = fmaxf(m3, __shfl_xor(m3, off));
    }
    float e0 = act ? __expf(a0 - m0) : 0.f;
    float e1 = act ? __expf(a1 - m1) : 0.f;
    float e2 = act ? __expf(a2 - m2) : 0.f;
    float e3 = act ? __expf(a3 - m3) : 0.f;
    float d0 = e0, d1 = e1, d2 = e2, d3 = e3;
    for (int off = 32; off; off >>= 1) {
      d0 += __shfl_xor(d0, off); d1 += __shfl_xor(d1, off);
      d2 += __shfl_xor(d2, off); d3 += __shfl_xor(d3, off);
    }
    float w0 = e0 * (1.f / (d0 + 1e-16f));
    float w1 = e1 * (1.f / (d1 + 1e-16f));
    float w2 = e2 * (1.f / (d2 + 1e-16f));
    float w3 = e3 * (1.f / (d3 + 1e-16f));
    // pack fp16 weights into two u32 lane-registers (inactive lanes: w=0)
    unsigned wy = (unsigned)f2h(w0) | ((unsigned)f2h(w1) << 16);
    unsigned wz = (unsigned)f2h(w2) | ((unsigned)f2h(w3) << 16);

#pragma unroll 4
    for (int j = 0; j < deg; ++j) {
      int sj2 = __builtin_amdgcn_readlane(srcr, j);              // scalar pipe
      unsigned uy = (unsigned)__builtin_amdgcn_readlane((int)wy, j);
      unsigned uz = (unsigned)__builtin_amdgcn_readlane((int)wz, j);
      float q0 = h2f((unsigned short)(uy & 0xffffu));
      float q1 = h2f((unsigned short)(uy >> 16));
      float q2 = h2f((unsigned short)(uz & 0xffffu));
      float q3 = h2f((unsigned short)(uz >> 16));
      const float* hr = h + (size_t)sj2 * DIM;
      float hv0 = hr[lane];
      float hv1 = has2 ? hr[64 + lane] : 0.f;
      A0 += q0 * hv0; A1 += q1 * hv0; A2 += q2 * hv0; A3 += q3 * hv0;
      B0 += q0 * hv1; B1 += q1 * hv1; B2 += q2 * hv1; B3 += q3 * hv1;
    }
  } else {
    // ---- generic path (deg > 64): 3-pass recompute (rare) ----
    float m0 = -1e30f, m1 = -1e30f, m2 = -1e30f, m3 = -1e30f;
    for (int p = start + lane; p < end; p += 64) {
      ALPHA_P(p)
      (void)s_;
      m0 = fmaxf(m0, a0); m1 = fmaxf(m1, a1); m2 = fmaxf(m2, a2); m3 = fmaxf(m3, a3);
    }
    for (int off = 32; off; off >>= 1) {
      m0 = fmaxf(m0, __shfl_xor(m0, off));
      m1 = fmaxf(m1, __shfl_xor(m1, off));
      m2 = fmaxf(m2, __shfl_xor(m2, off));
      m3 = fmaxf(m3, __shfl_xor(m3, off));
    }
    float d0 = 0.f, d1 = 0.f, d2 = 0.f, d3 = 0.f;
    for (int p = start + lane; p < end; p += 64) {
      ALPHA_P(p)
      (void)s_;
      d0 += __expf(a0 - m0); d1 += __expf(a1 - m1);
      d2 += __expf(a2 - m2); d3 += __expf(a3 - m3);
    }
    for (int off = 32; off; off >>= 1) {
      d0 += __shfl_xor(d0, off); d1 += __shfl_xor(d1, off);
      d2 += __shfl_xor(d2, off); d3 += __shfl_xor(d3, off);
    }
    float i0 = 1.f / (d0 + 1e-16f), i1 = 1.f / (d1 + 1e-16f);
    float i2 = 1.f / (d2 + 1e-16f), i3 = 1.f / (d3 + 1e-16f);
    for (int base = start; base < end; base += 64) {
      int cntv = min(64, end - base);
      int p = base + lane;
      float w0 = 0.f, w1 = 0.f, w2 = 0.f, w3 = 0.f;
      int srcr = 0;
      if (p < end) {
        ALPHA_P(p)
        w0 = __expf(a0 - m0) * i0; w1 = __expf(a1 - m1) * i1;
        w2 = __expf(a2 - m2) * i2; w3 = __expf(a3 - m3) * i3;
        srcr = s_;
      }
      for (int j = 0; j < cntv; ++j) {
        int sj2 = __shfl(srcr, j);
        float q0 = __shfl(w0, j), q1 = __shfl(w1, j);
        float q2 = __shfl(w2, j), q3 = __shfl(w3, j);
        const float* hr = h + (size_t)sj2 * DIM;
        float hv0 = hr[lane];
        float hv1 = has2 ? hr[64 + lane] : 0.f;
        A0 += q0 * hv0; A1 += q1 * hv0; A2 += q2 * hv0; A3 += q3 * hv0;
        B0 += q0 * hv1; B1 += q1 * hv1; B2 += q2 * hv1; B3 += q3 * hv1;
      }
    }
  }
  unsigned short* outp = agg2h + (size_t)n * KP;
  outp[lane] = f2h(A0); outp[100 + lane] = f2h(A1);
  outp[200 + lane] = f2h(A2); outp[300 + lane] = f2h(A3);
  if (has2) {
    outp[64 + lane] = f2h(B0); outp[164 + lane] = f2h(B1);
    outp[264 + lane] = f2h(B2); outp[364 + lane] = f2h(B3);
  }
  if (lane < KP - 400) outp[400 + lane] = 0;   // zero K-pad for MFMA
}

// GEMM2 via MFMA f16: C[30000,100] = agg2h[30000,416] @ B[416,112(pad)]
// No LDS. Wave = 16 rows x 7 col-tiles; A-frag 16B coalesced loads, B-frag
// pre-packed in operand order. Fused LayerNorm + ELU + residual epilogue.
__global__ __launch_bounds__(256) void k_gemm2(const _Float16* __restrict__ agg2h,
                                               const _Float16* __restrict__ Bfrag_l,
                                               const float* __restrict__ lg,
                                               const float* __restrict__ lb,
                                               float* __restrict__ h) {
  int t = threadIdx.x;
  int lane = t & 63;
  int w = t >> 6;
  int c = lane & 15;        // col within tile / A-row within tile
  int quad = lane >> 4;
  int nb = blockIdx.x * 64 + w * 16;     // wave's 16 rows

  f32x4 acc[7];
#pragma unroll
  for (int ct = 0; ct < 7; ++ct) acc[ct] = (f32x4){0.f, 0.f, 0.f, 0.f};

  const _Float16* arow = agg2h + (size_t)(nb + c) * KP + quad * 8;
#pragma unroll
  for (int ks = 0; ks < 13; ++ks) {
    half8 a = *(const half8*)(arow + ks * 32);
    const _Float16* bp = Bfrag_l + (size_t)(ks * 64 + lane) * 8;
#pragma unroll
    for (int ct = 0; ct < 7; ++ct) {
      half8 b = *(const half8*)(bp + (size_t)ct * 13 * 64 * 8);
      acc[ct] = __builtin_amdgcn_mfma_f32_16x16x32_f16(a, b, acc[ct], 0, 0, 0);
    }
  }

  // epilogue: C/D layout col=lane&15, row=quad*4+reg. LN across the 16 lanes
  // of a quad (xor 1,2,4,8 stays inside the 16-lane group).
  float gv[7], bv[7];
#pragma unroll
  for (int ct = 0; ct < 7; ++ct) {
    int col = ct * 16 + c;
    gv[ct] = (col < DIM) ? lg[col] : 0.f;
    bv[ct] = (col < DIM) ? lb[col] : 0.f;
  }
  bool c4 = c < 4;   // ct=6 valid cols: 96..99
#pragma unroll
  for (int r = 0; r < 4; ++r) {
    int n = nb + quad * 4 + r;
    float v[7];
#pragma unroll
    for (int ct = 0; ct < 7; ++ct) v[ct] = acc[ct][r];
    float s = v[0] + v[1] + v[2] + v[3] + v[4] + v[5] + (c4 ? v[6] : 0.f);
    s += __shfl_xor(s, 1); s += __shfl_xor(s, 2);
    s += __shfl_xor(s, 4); s += __shfl_xor(s, 8);
    float mu = s * 0.01f;
    float dv[7];
    float s2 = 0.f;
#pragma unroll
    for (int ct = 0; ct < 6; ++ct) { dv[ct] = v[ct] - mu; s2 += dv[ct] * dv[ct]; }
    dv[6] = c4 ? (v[6] - mu) : 0.f;
    s2 += dv[6] * dv[6];
    s2 += __shfl_xor(s2, 1); s2 += __shfl_xor(s2, 2);
    s2 += __shfl_xor(s2, 4); s2 += __shfl_xor(s2, 8);
    float rstd = rsqrtf(s2 * 0.01f + 1e-5f);
    if (n < N_NODES) {
      float* hp = h + (size_t)n * DIM;
#pragma unroll
      for (int ct = 0; ct < 7; ++ct) {
        int col = ct * 16 + c;
        if (ct < 6 || c4) {
          float y = dv[ct] * rstd * gv[ct] + bv[ct];
          y = y > 0.f ? y : (__expf(y) - 1.f);
          hp[col] += y;
        }
      }
    }
  }
}

// pool via run-length accumulation (batch is sorted): ~2 atomics/dim/block
__global__ __launch_bounds__(128) void k_pool(const float* __restrict__ h,
                                              const int* __restrict__ batch,
                                              float* __restrict__ pooled, float* __restrict__ cnt) {
  int d = threadIdx.x;
  int n0 = blockIdx.x * 64;
  int n1 = min(n0 + 64, N_NODES);
  if (n0 >= N_NODES) return;
  int curg = -1;
  float acc = 0.f, c = 0.f;
  for (int n = n0; n < n1; ++n) {
    int g = batch[n];
    if (g != curg) {
      if (curg >= 0) {
        if (d < 100) atomicAdd(&pooled[(size_t)curg * DIM + d], acc);
        if (d == 0) atomicAdd(&cnt[curg], c);
      }
      curg = g; acc = 0.f; c = 0.f;
    }
    if (d < 100) acc += h[(size_t)n * DIM + d];
    c += 1.f;
  }
  if (curg >= 0) {
    if (d < 100) atomicAdd(&pooled[(size_t)curg * DIM + d], acc);
    if (d == 0) atomicAdd(&cnt[curg], c);
  }
}

__global__ __launch_bounds__(64) void k_mlp(const float* __restrict__ pooled,
                                            const float* __restrict__ cnt,
                                            const float* __restrict__ w1, const float* __restrict__ b1,
                                            const float* __restrict__ w2, const float* __restrict__ b2,
                                            float* __restrict__ out) {
  int g = blockIdx.x;
  int j = threadIdx.x;
  float invc = 1.0f / fmaxf(cnt[g], 1.0f);
  const float* pr = pooled + (size_t)g * DIM;
  const float* wr = w1 + (size_t)j * DIM;
  float acc = 0.f;
  for (int k = 0; k < DIM; ++k) acc += pr[k] * wr[k];
  float hh = acc * invc + b1[j];
  out[NG + g * 64 + j] = hh;
  float v = hh * w2[j];
  for (int off = 32; off; off >>= 1) v += __shfl_xor(v, off);
  if (j == 0) out[g] = v + b2[0];
}

// ---------------------------------------------------------------------------
extern "C" void kernel_launch(void* const* d_in, const int* in_sizes, int n_in,
                              void* d_out, int out_size, void* d_ws, size_t ws_size,
                              hipStream_t stream) {
  (void)in_sizes; (void)n_in; (void)out_size; (void)ws_size;
  const int* x = (const int*)d_in[0];
  const int* ei = (const int*)d_in[1];
  const float* ea = (const float*)d_in[2];
  const int* batch = (const int*)d_in[3];
  const float* emb = (const float*)d_in[4];
  const float* W = (const float*)d_in[5];
  const float* We = (const float*)d_in[6];
  const float* a = (const float*)d_in[7];
  const float* ln_g = (const float*)d_in[8];
  const float* ln_b = (const float*)d_in[9];
  const float* w1 = (const float*)d_in[10];
  const float* b1 = (const float*)d_in[11];
  const float* w2 = (const float*)d_in[12];
  const float* b2 = (const float*)d_in[13];
  float* outp = (float*)d_out;

  char* ws = (char*)d_ws;
  float* h = (float*)(ws + OFF_H);
  unsigned short* agg2h = (unsigned short*)(ws + OFF_AGG2);
  int* csr_eid = (int*)(ws + OFF_EID);
  int* deg = (int*)(ws + OFF_DEG);
  int* cursor = (int*)(ws + OFF_CURS);
  unsigned short* esc_tmp = (unsigned short*)(ws + OFF_ETMP);
  float* pooled = (float*)(ws + OFF_POOL);
  float* cnt = (float*)(ws + OFF_CNT);
  float* sc_i = (float*)(ws + OFF_SCI);
  float* sc_j = (float*)(ws + OFF_SCJ);
  unsigned short* esc = (unsigned short*)(ws + OFF_ESC);
  float* cWij = (float*)(ws + OFF_CWIJ);
  unsigned short* Bw = (unsigned short*)(ws + OFF_BW);
  unsigned short* Bfrag = (unsigned short*)(ws + OFF_WR);
  int* indptr = (int*)(ws + OFF_INDPTR);
  int* csr_src = (int*)(ws + OFF_CSRS);
  int* bsum = (int*)(ws + OFF_BSUM);

  k_init<<<11719, 256, 0, stream>>>(x, emb, h, deg, cursor);
  k_fold<<<61, 256, 0, stream>>>(W, We, a, cWij, Bw);
  k_bfrag<<<1092, 256, 0, stream>>>(W, Bfrag);
  k_deg<<<1993, 256, 0, stream>>>(ei, deg);
  k_scan1<<<30, 1024, 0, stream>>>(deg, indptr, bsum);
  k_scan2<<<1, 64, 0, stream>>>(bsum);
  k_scan3<<<30, 1024, 0, stream>>>(indptr, bsum);
  k_scatter<<<1993, 256, 0, stream>>>(ei, indptr, cursor, csr_src, csr_eid);
  k_escore<<<7500, 256, 0, stream>>>(ea, Bw, esc_tmp);
  k_permute<<<1993, 256, 0, stream>>>(esc_tmp, csr_eid, esc);

  for (int l = 0; l < NL; ++l) {
    k_score<<<118, 256, 0, stream>>>(h, cWij + l * 800, sc_i, sc_j);
    k_aggr<<<7500, 256, 0, stream>>>(h, sc_i, sc_j, esc + (size_t)l * EP_EDGES * 4,
                                     indptr, csr_src, agg2h);
    k_gemm2<<<469, 256, 0, stream>>>((const _Float16*)agg2h,
                                     (const _Float16*)(Bfrag + (size_t)l * 7 * 13 * 64 * 8),
                                     ln_g + l * 100, ln_b + l * 100, h);
  }

  hipMemsetAsync(ws + OFF_POOL, 0, 51200 + 512, stream);
  k_pool<<<469, 128, 0, stream>>>(h, batch, pooled, cnt);
  k_mlp<<<128, 64, 0, stream>>>(pooled, cnt, w1, b1, w2, b2, outp);
}

// Round 8
// 820.226 us; speedup vs baseline: 1.1629x; 1.0696x over previous
//
#include <hip/hip_runtime.h>
#include <cstdint>
#include <cstddef>

#define N_NODES 30000
#define N_EDGES 480000
#define EP_EDGES (N_EDGES + N_NODES)   // 510000, with self-loops appended
#define DIM 100
#define NH 4
#define NL 6
#define NG 128
#define KP 416                         // GEMM2 K padded to 13*32

// ---------------------------------------------------------------------------
// Workspace layout (bytes). Peak ~88.6 MB (known-good bound: 112.5 MB).
#define OFF_H       0u            // float [30000][100]
#define OFF_AGG2    12000000u     // fp16  [30000][416]  (24.96 MB, loop only)
#define OFF_EID     12000000u     // int   [510000]   (overlay, pre-loop: csr slot -> edge id, -1=self-loop)
#define OFF_DEG     14040000u     // int   [30000]    (overlay, pre-loop)
#define OFF_CURS    14160000u     // int   [30000]    (overlay, pre-loop)
#define OFF_ETMP    16000000u     // fp16  [480000][24] edge-order scores (overlay, pre-loop, 23.04 MB)
#define OFF_POOL    12000000u     // float [128][100] (overlay, post-loop)
#define OFF_CNT     12051200u     // float [128]      (overlay, post-loop)
#define OFF_SCI     60000000u     // float [30000][4]
#define OFF_SCJ     60480000u     // float [30000][4]
#define OFF_ESC     60960000u     // fp16  [6][510000][4]  (CSR order!)
#define OFF_CWIJ    85440000u     // float [6][100][8]  (c = isJ*4 + h)
#define OFF_WR      85469184u     // fp16  Bfrag [6][7][13][64][8]  (559 KB)
#define OFF_INDPTR  86429184u     // int   [30001]
#define OFF_CSRS    86549248u     // int   [510000]
#define OFF_BSUM    88589248u     // int   [32]
#define OFF_BW      88589376u     // fp16  Bw [2(hl)][2(ct)][4(ks)][64][8]  (16 KB, escore MFMA B)

typedef _Float16 half8 __attribute__((ext_vector_type(8)));
typedef __fp16 fp16x2 __attribute__((ext_vector_type(2)));
typedef float f32x4 __attribute__((ext_vector_type(4)));

static __device__ __forceinline__ unsigned short f2h(float f) {
  return __builtin_bit_cast(unsigned short, (_Float16)f);
}
static __device__ __forceinline__ float h2f(unsigned short u) {
  return (float)__builtin_bit_cast(_Float16, u);
}

// ---------------------------------------------------------------------------
__global__ __launch_bounds__(256) void k_init(const int* __restrict__ x,
                                              const float* __restrict__ emb,
                                              float* __restrict__ h,
                                              int* __restrict__ deg, int* __restrict__ cursor) {
  int tid = blockIdx.x * 256 + threadIdx.x;
  if (tid < N_NODES * DIM) {
    int n = tid / DIM;
    int d = tid - n * DIM;
    h[tid] = emb[x[n] * DIM + d];
  }
  if (tid < N_NODES) { deg[tid] = 0; cursor[tid] = 0; }
}

// fold W,We with a_i/a_j:
//  - cWij[l][k][c] (c=isJ*4+h)  for k_score
//  - Bw: escore MFMA B-operand, split precision (hl=0: f16(v), hl=1: f16(v-f32(f16(v)))).
//    Entry (hl,ct,ks,lane,j) = folded We.a_j for col c=ct*16+(lane&15) (=l*4+h),
//    k = ks*32 + (lane>>4)*8 + j; zero outside c<24 || k<100.
__global__ __launch_bounds__(256) void k_fold(const float* __restrict__ W,
                                              const float* __restrict__ We,
                                              const float* __restrict__ a,
                                              float* __restrict__ cWij,
                                              unsigned short* __restrict__ Bw) {
  int tid = blockIdx.x * 256 + threadIdx.x;
  if (tid < NL * DIM * 8) {
    int l = tid / 800, r = tid % 800;
    int k = r >> 3, c = r & 7;
    int hh = c & 3, isJ = c >> 2;
    const float* wp = W + (size_t)(l * 400 + hh * 100) * 100 + k;
    const float* ap = a + (size_t)(l * 4 + hh) * 200 + isJ * 100;
    float s = 0.f;
    for (int d = 0; d < 100; ++d) s += wp[(size_t)d * 100] * ap[d];
    cWij[l * 800 + k * 8 + c] = s;
  } else if (tid < NL * DIM * 8 + DIM * 24) {
    int m = tid - NL * DIM * 8;
    int k = m / 24, c = m % 24;
    int l = c >> 2, hh = c & 3;
    const float* wp = We + (size_t)(l * 400 + hh * 100) * 100 + k;
    const float* ap = a + (size_t)(l * 4 + hh) * 200 + 100;
    float s = 0.f;
    for (int d = 0; d < 100; ++d) s += wp[(size_t)d * 100] * ap[d];
    // split precision + scatter into MFMA B-operand order
    _Float16 vh = (_Float16)s;
    _Float16 vl = (_Float16)(s - (float)vh);
    int ct = c >> 4;
    int lane = (((k & 31) >> 3) << 4) | (c & 15);
    int ks = k >> 5;
    int j = k & 7;
    Bw[(size_t)(((0 * 2 + ct) * 4 + ks) * 64 + lane) * 8 + j] = __builtin_bit_cast(unsigned short, vh);
    Bw[(size_t)(((1 * 2 + ct) * 4 + ks) * 64 + lane) * 8 + j] = __builtin_bit_cast(unsigned short, vl);
  } else if (tid < NL * DIM * 8 + DIM * 24 + 8192) {
    // zero-fill the invalid (padding) Bw entries; disjoint from valid writes.
    int E = tid - (NL * DIM * 8 + DIM * 24);
    int j = E & 7;
    int lane = (E >> 3) & 63;
    int rest = E >> 9;          // [0,16)
    int ks = rest & 3;
    int ct = (rest >> 2) & 1;
    int c = ct * 16 + (lane & 15);
    int k = ks * 32 + ((lane >> 4) << 3) + j;
    if (!(c < 24 && k < 100)) Bw[E] = 0;
  }
}

// Bfrag[l][ct][ks][lane][j] (f16) = B[k][n] in MFMA B-operand order:
//   k = ks*32 + (lane>>4)*8 + j,  n = ct*16 + (lane&15)
//   B[k=hh*100+kk][n] = W[l][hh*100 + n][kk]   (zeros in pads)
__global__ __launch_bounds__(256) void k_bfrag(const float* __restrict__ W,
                                               unsigned short* __restrict__ Bfrag) {
  int tid = blockIdx.x * 256 + threadIdx.x;
  if (tid >= NL * 7 * 13 * 64 * 8) return;
  int j = tid & 7;
  int lane = (tid >> 3) & 63;
  int rest = tid >> 9;          // ((l*7+ct)*13+ks)
  int ks = rest % 13;
  int rest2 = rest / 13;
  int ct = rest2 % 7;
  int l = rest2 / 7;
  int k = ks * 32 + ((lane >> 4) << 3) + j;
  int n = ct * 16 + (lane & 15);
  float v = 0.f;
  if (k < 400 && n < 100) {
    int hh = k / 100, kk = k - hh * 100;
    v = W[(size_t)(l * 400 + hh * 100 + n) * 100 + kk];
  }
  Bfrag[tid] = f2h(v);
}

__global__ __launch_bounds__(256) void k_deg(const int* __restrict__ ei, int* __restrict__ deg) {
  int tid = blockIdx.x * 256 + threadIdx.x;
  if (tid >= EP_EDGES) return;
  int dstn = (tid < N_EDGES) ? ei[N_EDGES + tid] : (tid - N_EDGES);
  atomicAdd(&deg[dstn], 1);
}

// two-level scan: per-block inclusive scan (30 blocks x 1024)
__global__ __launch_bounds__(1024) void k_scan1(const int* __restrict__ deg,
                                                int* __restrict__ indptr, int* __restrict__ bsum) {
  __shared__ int s[1024];
  int t = threadIdx.x;
  int i = blockIdx.x * 1024 + t;
  int v = (i < N_NODES) ? deg[i] : 0;
  s[t] = v;
  __syncthreads();
  for (int off = 1; off < 1024; off <<= 1) {
    int tmp = (t >= off) ? s[t - off] : 0;
    __syncthreads();
    s[t] += tmp;
    __syncthreads();
  }
  if (i < N_NODES) indptr[i + 1] = s[t];
  if (t == 1023) bsum[blockIdx.x] = s[1023];
}
// scan 30 block sums -> exclusive offsets (1 wave)
__global__ __launch_bounds__(64) void k_scan2(int* __restrict__ bsum) {
  int t = threadIdx.x;
  int v = (t < 30) ? bsum[t] : 0;
  int inc = v;
  for (int off = 1; off < 64; off <<= 1) {
    int up = __shfl_up(inc, off);
    if (t >= off) inc += up;
  }
  if (t < 30) bsum[t] = inc - v;   // exclusive
}
__global__ __launch_bounds__(1024) void k_scan3(int* __restrict__ indptr,
                                                const int* __restrict__ bsum) {
  int i = blockIdx.x * 1024 + threadIdx.x;
  if (i < N_NODES) indptr[i + 1] += bsum[blockIdx.x];
  if (i == 0) indptr[0] = 0;
}

// build CSR; record inverse permutation csr_eid[p] = edge id (-1 for self-loop)
__global__ __launch_bounds__(256) void k_scatter(const int* __restrict__ ei,
                                                 const int* __restrict__ indptr,
                                                 int* __restrict__ cursor,
                                                 int* __restrict__ csr_src,
                                                 int* __restrict__ csr_eid) {
  int tid = blockIdx.x * 256 + threadIdx.x;
  if (tid >= EP_EDGES) return;
  int dstn = (tid < N_EDGES) ? ei[N_EDGES + tid] : (tid - N_EDGES);
  int srcn = (tid < N_EDGES) ? ei[tid] : (tid - N_EDGES);
  int p = indptr[dstn] + atomicAdd(&cursor[dstn], 1);
  csr_src[p] = srcn;
  csr_eid[p] = (tid < N_EDGES) ? tid : -1;
}

// esc_tmp[e][l*4+h] = fp16( edge_attr[e,:] . cWe[l*4+h,:] ), EDGE order, via
// MFMA 16x16x32 f16 with split-precision compensation:
//   score = xh@wh + xl@wh + xh@wl   (residual ~2^-20 rel; f32-equivalent)
// B-operand (weights, 16 half8) lives in VGPRs for the whole kernel.
// A: 64 edge rows staged f32 into XOR-swizzled LDS (conflict-free b128 reads),
// hi/lo split on the fly. One-shot blocks: 7500 x 256 (4 waves, wave = 16 rows).
__global__ __launch_bounds__(256, 4) void k_escore(const float* __restrict__ ea,
                                                   const unsigned short* __restrict__ Bw,
                                                   unsigned short* __restrict__ esc_tmp) {
  __shared__ __align__(16) float s_ea[64 * 128];   // 32 KB, [row][128 f32], swizzled
  int t = threadIdx.x;
  int lane = t & 63;
  int wv = t >> 6;

  // ---- B fragments: load once, keep in VGPRs (16 half8 = 64 VGPRs) ----
  const half8* bp = (const half8*)Bw;
  half8 Bh[2][4], Bl[2][4];
#pragma unroll
  for (int ct = 0; ct < 2; ++ct)
#pragma unroll
    for (int ks = 0; ks < 4; ++ks) {
      Bh[ct][ks] = bp[((0 * 2 + ct) * 4 + ks) * 64 + lane];
      Bl[ct][ks] = bp[((1 * 2 + ct) * 4 + ks) * 64 + lane];
    }

  // ---- stage tile: zero K-pad chunks + 64 rows x 25 float4, swizzled ----
  int e0 = blockIdx.x * 64;
  const float4* g4 = (const float4*)(ea + (size_t)e0 * 100);
  for (int z = t; z < 448; z += 256) {          // rows x chunks 25..31 (k 100..127)
    int zr = z / 7, zc = z - zr * 7;
    int o = 400 + zc * 16;
    *(float4*)((char*)s_ea + zr * 512 + (o ^ ((zr & 7) << 4))) = (float4){0.f, 0.f, 0.f, 0.f};
  }
#pragma unroll
  for (int i = 0; i < 7; ++i) {
    int v = i * 256 + t;
    if (i < 6 || v < 1600) {
      float4 val = g4[v];
      int r = v / 25, kk = v - r * 25;
      *(float4*)((char*)s_ea + r * 512 + ((kk * 16) ^ ((r & 7) << 4))) = val;
    }
  }
  __syncthreads();

  // ---- MFMA main: wave wv handles edge rows wv*16 .. +15 ----
  int c = lane & 15;
  int quad = lane >> 4;
  int lrow = wv * 16 + c;                 // A-operand row for this lane
  int swz = (lrow & 7) << 4;
  const char* base = (const char*)s_ea + lrow * 512;
  f32x4 acc0 = (f32x4){0.f, 0.f, 0.f, 0.f};
  f32x4 acc1 = (f32x4){0.f, 0.f, 0.f, 0.f};
#pragma unroll
  for (int ks = 0; ks < 4; ++ks) {
    int o = ks * 128 + quad * 32;
    float4 xa = *(const float4*)(base + ((o) ^ swz));
    float4 xb = *(const float4*)(base + ((o + 16) ^ swz));
    fp16x2 h0 = __builtin_amdgcn_cvt_pkrtz(xa.x, xa.y);
    fp16x2 h1 = __builtin_amdgcn_cvt_pkrtz(xa.z, xa.w);
    fp16x2 h2 = __builtin_amdgcn_cvt_pkrtz(xb.x, xb.y);
    fp16x2 h3 = __builtin_amdgcn_cvt_pkrtz(xb.z, xb.w);
    fp16x2 l0 = __builtin_amdgcn_cvt_pkrtz(xa.x - (float)h0[0], xa.y - (float)h0[1]);
    fp16x2 l1 = __builtin_amdgcn_cvt_pkrtz(xa.z - (float)h1[0], xa.w - (float)h1[1]);
    fp16x2 l2 = __builtin_amdgcn_cvt_pkrtz(xb.x - (float)h2[0], xb.y - (float)h2[1]);
    fp16x2 l3 = __builtin_amdgcn_cvt_pkrtz(xb.z - (float)h3[0], xb.w - (float)h3[1]);
    uint4 uh = {__builtin_bit_cast(unsigned, h0), __builtin_bit_cast(unsigned, h1),
                __builtin_bit_cast(unsigned, h2), __builtin_bit_cast(unsigned, h3)};
    uint4 ul = {__builtin_bit_cast(unsigned, l0), __builtin_bit_cast(unsigned, l1),
                __builtin_bit_cast(unsigned, l2), __builtin_bit_cast(unsigned, l3)};
    half8 xh = __builtin_bit_cast(half8, uh);
    half8 xl = __builtin_bit_cast(half8, ul);
    acc0 = __builtin_amdgcn_mfma_f32_16x16x32_f16(xh, Bh[0][ks], acc0, 0, 0, 0);
    acc0 = __builtin_amdgcn_mfma_f32_16x16x32_f16(xl, Bh[0][ks], acc0, 0, 0, 0);
    acc0 = __builtin_amdgcn_mfma_f32_16x16x32_f16(xh, Bl[0][ks], acc0, 0, 0, 0);
    acc1 = __builtin_amdgcn_mfma_f32_16x16x32_f16(xh, Bh[1][ks], acc1, 0, 0, 0);
    acc1 = __builtin_amdgcn_mfma_f32_16x16x32_f16(xl, Bh[1][ks], acc1, 0, 0, 0);
    acc1 = __builtin_amdgcn_mfma_f32_16x16x32_f16(xh, Bl[1][ks], acc1, 0, 0, 0);
  }

  // ---- epilogue: C/D col=lane&15, row=quad*4+r. cols: ct0 -> c, ct1 -> 16+c ----
  unsigned short* orow = esc_tmp + (size_t)(e0 + wv * 16 + quad * 4) * 24;
#pragma unroll
  for (int r = 0; r < 4; ++r) {
    unsigned short* op = orow + r * 24;
    op[c] = f2h(acc0[r]);
    if (c < 8) op[16 + c] = f2h(acc1[r]);
  }
}

// permute edge-order scores into CSR order, all 6 layers per slot.
// Random 48B (one line) read per real edge; fully coalesced 6x8B writes.
// Self-loop slots (eid = -1) write zeros.
__global__ __launch_bounds__(256) void k_permute(const unsigned short* __restrict__ esc_tmp,
                                                 const int* __restrict__ csr_eid,
                                                 unsigned short* __restrict__ esc) {
  int p = blockIdx.x * 256 + threadIdx.x;
  if (p >= EP_EDGES) return;
  int e = csr_eid[p];
  ushort4 v[NL];
  if (e >= 0) {
    const unsigned short* rp = esc_tmp + (size_t)e * 24;
#pragma unroll
    for (int l = 0; l < NL; ++l) v[l] = *(const ushort4*)(rp + l * 4);
  } else {
#pragma unroll
    for (int l = 0; l < NL; ++l) { v[l].x = 0; v[l].y = 0; v[l].z = 0; v[l].w = 0; }
  }
#pragma unroll
  for (int l = 0; l < NL; ++l)
    *(ushort4*)(esc + ((size_t)l * EP_EDGES + p) * 4) = v[l];
}

// per-node attention scores: sc_i[n,h], sc_j[n,h]
__global__ __launch_bounds__(256) void k_score(const float* __restrict__ h,
                                               const float* __restrict__ cw,  // [100][8]
                                               float* __restrict__ sc_i, float* __restrict__ sc_j) {
  __shared__ __align__(16) float s[DIM * 8];
  for (int i = threadIdx.x; i < DIM * 8; i += 256) s[i] = cw[i];
  __syncthreads();
  int n = blockIdx.x * 256 + threadIdx.x;
  if (n >= N_NODES) return;
  float acc[8] = {0.f, 0.f, 0.f, 0.f, 0.f, 0.f, 0.f, 0.f};
  const float* hr = h + (size_t)n * DIM;
  for (int k4 = 0; k4 < 25; ++k4) {
    float4 v = *(const float4*)(hr + k4 * 4);
    float vv[4] = {v.x, v.y, v.z, v.w};
#pragma unroll
    for (int kk = 0; kk < 4; ++kk) {
      const float* sr = s + (k4 * 4 + kk) * 8;
#pragma unroll
      for (int c = 0; c < 8; ++c) acc[c] += vv[kk] * sr[c];
    }
  }
  *(float4*)(sc_i + (size_t)n * 4) = make_float4(acc[0], acc[1], acc[2], acc[3]);
  *(float4*)(sc_j + (size_t)n * 4) = make_float4(acc[4], acc[5], acc[6], acc[7]);
}

#define ALPHA_P(pp)                                                                  \
  int s_ = csr_src[pp];                                                              \
  float4 sj_ = *(const float4*)(sc_j + (size_t)s_ * 4);                              \
  ushort4 eb_ = *(const ushort4*)(esc_l + (size_t)(pp) * 4);                         \
  float a0 = si.x + sj_.x + h2f(eb_.x); a0 = a0 > 0.f ? a0 : 0.2f * a0;              \
  float a1 = si.y + sj_.y + h2f(eb_.y); a1 = a1 > 0.f ? a1 : 0.2f * a1;              \
  float a2 = si.z + sj_.z + h2f(eb_.z); a2 = a2 > 0.f ? a2 : 0.2f * a2;              \
  float a3 = si.w + sj_.w + h2f(eb_.w); a3 = a3 > 0.f ? a3 : 0.2f * a3;

// one wave per node: segment softmax + weighted gather of h[src].
// The j-loop is depth-3 software-pipelined with a branch-free clamped
// prefetch (min(j+3, deg-1)): 6 loads in flight per wave instead of 2.
// Per-node fma order identical to the known-good version (bitwise-same).
__global__ __launch_bounds__(256) void k_aggr(const float* __restrict__ h,
                                              const float* __restrict__ sc_i,
                                              const float* __restrict__ sc_j,
                                              const unsigned short* __restrict__ esc_l,
                                              const int* __restrict__ indptr,
                                              const int* __restrict__ csr_src,
                                              unsigned short* __restrict__ agg2h) {
  __shared__ __align__(16) uint4 s_pack[4][64];   // 4 KB, per-wave region
  int wave = threadIdx.x >> 6;
  int lane = threadIdx.x & 63;
  int n = blockIdx.x * 4 + wave;                  // 7500*4 == 30000: no early-out
  int start = indptr[n], end = indptr[n + 1];
  int deg = end - start;
  float4 si = *(const float4*)(sc_i + (size_t)n * 4);
  float A0 = 0.f, A1 = 0.f, A2 = 0.f, A3 = 0.f;
  float B0 = 0.f, B1 = 0.f, B2 = 0.f, B3 = 0.f;
  bool has2 = lane < (DIM - 64);

  if (deg <= 64) {
    // ---- fast path: one edge per lane, single alpha computation ----
    int p = start + lane;
    bool act = p < end;
    int srcr = 0;
    float a0 = -1e30f, a1 = -1e30f, a2 = -1e30f, a3 = -1e30f;
    if (act) {
      int s2 = csr_src[p];
      float4 sj2 = *(const float4*)(sc_j + (size_t)s2 * 4);
      ushort4 eb2 = *(const ushort4*)(esc_l + (size_t)p * 4);
      a0 = si.x + sj2.x + h2f(eb2.x); a0 = a0 > 0.f ? a0 : 0.2f * a0;
      a1 = si.y + sj2.y + h2f(eb2.y); a1 = a1 > 0.f ? a1 : 0.2f * a1;
      a2 = si.z + sj2.z + h2f(eb2.z); a2 = a2 > 0.f ? a2 : 0.2f * a2;
      a3 = si.w + sj2.w + h2f(eb2.w); a3 = a3 > 0.f ? a3 : 0.2f * a3;
      srcr = s2;
    }
    float m0 = a0, m1 = a1, m2 = a2, m3 = a3;
    for (int off = 32; off; off >>= 1) {
      m0 = fmaxf(m0, __shfl_xor(m0, off));
      m1 = fmaxf(m1, __shfl_xor(m1, off));
      m2 = fmaxf(m2, __shfl_xor(m2, off));
      m3 = fmaxf(m3, __shfl_xor(m3, off));
    }
    float e0 = act ? __expf(a0 - m0) : 0.f;
    float e1 = act ? __expf(a1 - m1) : 0.f;
    float e2 = act ? __expf(a2 - m2) : 0.f;
    float e3 = act ? __expf(a3 - m3) : 0.f;
    float d0 = e0, d1 = e1, d2 = e2, d3 = e3;
    for (int off = 32; off; off >>= 1) {
      d0 += __shfl_xor(d0, off); d1 += __shfl_xor(d1, off);
      d2 += __shfl_xor(d2, off); d3 += __shfl_xor(d3, off);
    }
    float w0 = e0 * (1.f / (d0 + 1e-16f));
    float w1 = e1 * (1.f / (d1 + 1e-16f));
    float w2 = e2 * (1.f / (d2 + 1e-16f));
    float w3 = e3 * (1.f / (d3 + 1e-16f));
    // pack (src, fp16 w0..w3) -> one 16B broadcast read per edge in j-loop
    uint4 pk;
    pk.x = (unsigned)srcr;
    pk.y = (unsigned)f2h(w0) | ((unsigned)f2h(w1) << 16);
    pk.z = (unsigned)f2h(w2) | ((unsigned)f2h(w3) << 16);
    pk.w = 0u;
    s_pack[wave][lane] = pk;   // wave-synchronous; compiler inserts lgkmcnt

    // ---- depth-3 pipelined gather: branch-free clamped prefetch ----
    int jm = deg - 1;          // deg >= 1 always (self-loop)
    uint4 cp0 = s_pack[wave][0];
    uint4 cp1 = s_pack[wave][min(1, jm)];
    uint4 cp2 = s_pack[wave][min(2, jm)];
    const float* hr0 = h + (size_t)cp0.x * DIM;
    const float* hr1 = h + (size_t)cp1.x * DIM;
    const float* hr2 = h + (size_t)cp2.x * DIM;
    float x0a = hr0[lane], x0b = has2 ? hr0[64 + lane] : 0.f;
    float x1a = hr1[lane], x1b = has2 ? hr1[64 + lane] : 0.f;
    float x2a = hr2[lane], x2b = has2 ? hr2[64 + lane] : 0.f;
#pragma unroll 3
    for (int j = 0; j < deg; ++j) {
      uint4 cpn = s_pack[wave][min(j + 3, jm)];       // prefetch j+3
      const float* hrn = h + (size_t)cpn.x * DIM;
      float xna = hrn[lane];
      float xnb = has2 ? hrn[64 + lane] : 0.f;
      float q0 = h2f((unsigned short)(cp0.y & 0xffffu));
      float q1 = h2f((unsigned short)(cp0.y >> 16));
      float q2 = h2f((unsigned short)(cp0.z & 0xffffu));
      float q3 = h2f((unsigned short)(cp0.z >> 16));
      A0 += q0 * x0a; A1 += q1 * x0a; A2 += q2 * x0a; A3 += q3 * x0a;
      B0 += q0 * x0b; B1 += q1 * x0b; B2 += q2 * x0b; B3 += q3 * x0b;
      cp0 = cp1; x0a = x1a; x0b = x1b;
      cp1 = cp2; x1a = x2a; x1b = x2b;
      cp2 = cpn; x2a = xna; x2b = xnb;
    }
  } else {
    // ---- generic path (deg > 64): 3-pass recompute (rare) ----
    float m0 = -1e30f, m1 = -1e30f, m2 = -1e30f, m3 = -1e30f;
    for (int p = start + lane; p < end; p += 64) {
      ALPHA_P(p)
      (void)s_;
      m0 = fmaxf(m0, a0); m1 = fmaxf(m1, a1); m2 = fmaxf(m2, a2); m3 = fmaxf(m3, a3);
    }
    for (int off = 32; off; off >>= 1) {
      m0 = fmaxf(m0, __shfl_xor(m0, off));
      m1 = fmaxf(m1, __shfl_xor(m1, off));
      m2 = fmaxf(m2, __shfl_xor(m2, off));
      m3 = fmaxf(m3, __shfl_xor(m3, off));
    }
    float d0 = 0.f, d1 = 0.f, d2 = 0.f, d3 = 0.f;
    for (int p = start + lane; p < end; p += 64) {
      ALPHA_P(p)
      (void)s_;
      d0 += __expf(a0 - m0); d1 += __expf(a1 - m1);
      d2 += __expf(a2 - m2); d3 += __expf(a3 - m3);
    }
    for (int off = 32; off; off >>= 1) {
      d0 += __shfl_xor(d0, off); d1 += __shfl_xor(d1, off);
      d2 += __shfl_xor(d2, off); d3 += __shfl_xor(d3, off);
    }
    float i0 = 1.f / (d0 + 1e-16f), i1 = 1.f / (d1 + 1e-16f);
    float i2 = 1.f / (d2 + 1e-16f), i3 = 1.f / (d3 + 1e-16f);
    for (int base = start; base < end; base += 64) {
      int cntv = min(64, end - base);
      int p = base + lane;
      float w0 = 0.f, w1 = 0.f, w2 = 0.f, w3 = 0.f;
      int srcr = 0;
      if (p < end) {
        ALPHA_P(p)
        w0 = __expf(a0 - m0) * i0; w1 = __expf(a1 - m1) * i1;
        w2 = __expf(a2 - m2) * i2; w3 = __expf(a3 - m3) * i3;
        srcr = s_;
      }
      for (int j = 0; j < cntv; ++j) {
        int sj2 = __shfl(srcr, j);
        float q0 = __shfl(w0, j), q1 = __shfl(w1, j);
        float q2 = __shfl(w2, j), q3 = __shfl(w3, j);
        const float* hr = h + (size_t)sj2 * DIM;
        float hv0 = hr[lane];
        float hv1 = has2 ? hr[64 + lane] : 0.f;
        A0 += q0 * hv0; A1 += q1 * hv0; A2 += q2 * hv0; A3 += q3 * hv0;
        B0 += q0 * hv1; B1 += q1 * hv1; B2 += q2 * hv1; B3 += q3 * hv1;
      }
    }
  }
  unsigned short* outp = agg2h + (size_t)n * KP;
  outp[lane] = f2h(A0); outp[100 + lane] = f2h(A1);
  outp[200 + lane] = f2h(A2); outp[300 + lane] = f2h(A3);
  if (has2) {
    outp[64 + lane] = f2h(B0); outp[164 + lane] = f2h(B1);
    outp[264 + lane] = f2h(B2); outp[364 + lane] = f2h(B3);
  }
  if (lane < KP - 400) outp[400 + lane] = 0;   // zero K-pad for MFMA
}

// GEMM2 via MFMA f16: C[30000,100] = agg2h[30000,416] @ B[416,112(pad)]
// No LDS. Wave = 16 rows x 7 col-tiles; A-frag 16B coalesced loads, B-frag
// pre-packed in operand order. Fused LayerNorm + ELU + residual epilogue.
__global__ __launch_bounds__(256) void k_gemm2(const _Float16* __restrict__ agg2h,
                                               const _Float16* __restrict__ Bfrag_l,
                                               const float* __restrict__ lg,
                                               const float* __restrict__ lb,
                                               float* __restrict__ h) {
  int t = threadIdx.x;
  int lane = t & 63;
  int w = t >> 6;
  int c = lane & 15;        // col within tile / A-row within tile
  int quad = lane >> 4;
  int nb = blockIdx.x * 64 + w * 16;     // wave's 16 rows

  f32x4 acc[7];
#pragma unroll
  for (int ct = 0; ct < 7; ++ct) acc[ct] = (f32x4){0.f, 0.f, 0.f, 0.f};

  const _Float16* arow = agg2h + (size_t)(nb + c) * KP + quad * 8;
#pragma unroll
  for (int ks = 0; ks < 13; ++ks) {
    half8 a = *(const half8*)(arow + ks * 32);
    const _Float16* bp = Bfrag_l + (size_t)(ks * 64 + lane) * 8;
#pragma unroll
    for (int ct = 0; ct < 7; ++ct) {
      half8 b = *(const half8*)(bp + (size_t)ct * 13 * 64 * 8);
      acc[ct] = __builtin_amdgcn_mfma_f32_16x16x32_f16(a, b, acc[ct], 0, 0, 0);
    }
  }

  // epilogue: C/D layout col=lane&15, row=quad*4+reg. LN across the 16 lanes
  // of a quad (xor 1,2,4,8 stays inside the 16-lane group).
  float gv[7], bv[7];
#pragma unroll
  for (int ct = 0; ct < 7; ++ct) {
    int col = ct * 16 + c;
    gv[ct] = (col < DIM) ? lg[col] : 0.f;
    bv[ct] = (col < DIM) ? lb[col] : 0.f;
  }
  bool c4 = c < 4;   // ct=6 valid cols: 96..99
#pragma unroll
  for (int r = 0; r < 4; ++r) {
    int n = nb + quad * 4 + r;
    float v[7];
#pragma unroll
    for (int ct = 0; ct < 7; ++ct) v[ct] = acc[ct][r];
    float s = v[0] + v[1] + v[2] + v[3] + v[4] + v[5] + (c4 ? v[6] : 0.f);
    s += __shfl_xor(s, 1); s += __shfl_xor(s, 2);
    s += __shfl_xor(s, 4); s += __shfl_xor(s, 8);
    float mu = s * 0.01f;
    float dv[7];
    float s2 = 0.f;
#pragma unroll
    for (int ct = 0; ct < 6; ++ct) { dv[ct] = v[ct] - mu; s2 += dv[ct] * dv[ct]; }
    dv[6] = c4 ? (v[6] - mu) : 0.f;
    s2 += dv[6] * dv[6];
    s2 += __shfl_xor(s2, 1); s2 += __shfl_xor(s2, 2);
    s2 += __shfl_xor(s2, 4); s2 += __shfl_xor(s2, 8);
    float rstd = rsqrtf(s2 * 0.01f + 1e-5f);
    if (n < N_NODES) {
      float* hp = h + (size_t)n * DIM;
#pragma unroll
      for (int ct = 0; ct < 7; ++ct) {
        int col = ct * 16 + c;
        if (ct < 6 || c4) {
          float y = dv[ct] * rstd * gv[ct] + bv[ct];
          y = y > 0.f ? y : (__expf(y) - 1.f);
          hp[col] += y;
        }
      }
    }
  }
}

// pool via run-length accumulation (batch is sorted): ~2 atomics/dim/block
__global__ __launch_bounds__(128) void k_pool(const float* __restrict__ h,
                                              const int* __restrict__ batch,
                                              float* __restrict__ pooled, float* __restrict__ cnt) {
  int d = threadIdx.x;
  int n0 = blockIdx.x * 64;
  int n1 = min(n0 + 64, N_NODES);
  if (n0 >= N_NODES) return;
  int curg = -1;
  float acc = 0.f, c = 0.f;
  for (int n = n0; n < n1; ++n) {
    int g = batch[n];
    if (g != curg) {
      if (curg >= 0) {
        if (d < 100) atomicAdd(&pooled[(size_t)curg * DIM + d], acc);
        if (d == 0) atomicAdd(&cnt[curg], c);
      }
      curg = g; acc = 0.f; c = 0.f;
    }
    if (d < 100) acc += h[(size_t)n * DIM + d];
    c += 1.f;
  }
  if (curg >= 0) {
    if (d < 100) atomicAdd(&pooled[(size_t)curg * DIM + d], acc);
    if (d == 0) atomicAdd(&cnt[curg], c);
  }
}

__global__ __launch_bounds__(64) void k_mlp(const float* __restrict__ pooled,
                                            const float* __restrict__ cnt,
                                            const float* __restrict__ w1, const float* __restrict__ b1,
                                            const float* __restrict__ w2, const float* __restrict__ b2,
                                            float* __restrict__ out) {
  int g = blockIdx.x;
  int j = threadIdx.x;
  float invc = 1.0f / fmaxf(cnt[g], 1.0f);
  const float* pr = pooled + (size_t)g * DIM;
  const float* wr = w1 + (size_t)j * DIM;
  float acc = 0.f;
  for (int k = 0; k < DIM; ++k) acc += pr[k] * wr[k];
  float hh = acc * invc + b1[j];
  out[NG + g * 64 + j] = hh;
  float v = hh * w2[j];
  for (int off = 32; off; off >>= 1) v += __shfl_xor(v, off);
  if (j == 0) out[g] = v + b2[0];
}

// ---------------------------------------------------------------------------
extern "C" void kernel_launch(void* const* d_in, const int* in_sizes, int n_in,
                              void* d_out, int out_size, void* d_ws, size_t ws_size,
                              hipStream_t stream) {
  (void)in_sizes; (void)n_in; (void)out_size; (void)ws_size;
  const int* x = (const int*)d_in[0];
  const int* ei = (const int*)d_in[1];
  const float* ea = (const float*)d_in[2];
  const int* batch = (const int*)d_in[3];
  const float* emb = (const float*)d_in[4];
  const float* W = (const float*)d_in[5];
  const float* We = (const float*)d_in[6];
  const float* a = (const float*)d_in[7];
  const float* ln_g = (const float*)d_in[8];
  const float* ln_b = (const float*)d_in[9];
  const float* w1 = (const float*)d_in[10];
  const float* b1 = (const float*)d_in[11];
  const float* w2 = (const float*)d_in[12];
  const float* b2 = (const float*)d_in[13];
  float* outp = (float*)d_out;

  char* ws = (char*)d_ws;
  float* h = (float*)(ws + OFF_H);
  unsigned short* agg2h = (unsigned short*)(ws + OFF_AGG2);
  int* csr_eid = (int*)(ws + OFF_EID);
  int* deg = (int*)(ws + OFF_DEG);
  int* cursor = (int*)(ws + OFF_CURS);
  unsigned short* esc_tmp = (unsigned short*)(ws + OFF_ETMP);
  float* pooled = (float*)(ws + OFF_POOL);
  float* cnt = (float*)(ws + OFF_CNT);
  float* sc_i = (float*)(ws + OFF_SCI);
  float* sc_j = (float*)(ws + OFF_SCJ);
  unsigned short* esc = (unsigned short*)(ws + OFF_ESC);
  float* cWij = (float*)(ws + OFF_CWIJ);
  unsigned short* Bw = (unsigned short*)(ws + OFF_BW);
  unsigned short* Bfrag = (unsigned short*)(ws + OFF_WR);
  int* indptr = (int*)(ws + OFF_INDPTR);
  int* csr_src = (int*)(ws + OFF_CSRS);
  int* bsum = (int*)(ws + OFF_BSUM);

  k_init<<<11719, 256, 0, stream>>>(x, emb, h, deg, cursor);
  k_fold<<<61, 256, 0, stream>>>(W, We, a, cWij, Bw);
  k_bfrag<<<1092, 256, 0, stream>>>(W, Bfrag);
  k_deg<<<1993, 256, 0, stream>>>(ei, deg);
  k_scan1<<<30, 1024, 0, stream>>>(deg, indptr, bsum);
  k_scan2<<<1, 64, 0, stream>>>(bsum);
  k_scan3<<<30, 1024, 0, stream>>>(indptr, bsum);
  k_scatter<<<1993, 256, 0, stream>>>(ei, indptr, cursor, csr_src, csr_eid);
  k_escore<<<7500, 256, 0, stream>>>(ea, Bw, esc_tmp);
  k_permute<<<1993, 256, 0, stream>>>(esc_tmp, csr_eid, esc);

  for (int l = 0; l < NL; ++l) {
    k_score<<<118, 256, 0, stream>>>(h, cWij + l * 800, sc_i, sc_j);
    k_aggr<<<7500, 256, 0, stream>>>(h, sc_i, sc_j, esc + (size_t)l * EP_EDGES * 4,
                                     indptr, csr_src, agg2h);
    k_gemm2<<<469, 256, 0, stream>>>((const _Float16*)agg2h,
                                     (const _Float16*)(Bfrag + (size_t)l * 7 * 13 * 64 * 8),
                                     ln_g + l * 100, ln_b + l * 100, h);
  }

  hipMemsetAsync(ws + OFF_POOL, 0, 51200 + 512, stream);
  k_pool<<<469, 128, 0, stream>>>(h, batch, pooled, cnt);
  k_mlp<<<128, 64, 0, stream>>>(pooled, cnt, w1, b1, w2, b2, outp);
}